// Round 2
// baseline (3784.110 us; speedup 1.0000x reference)
//
#include <hip/hip_runtime.h>
#include <hip/hip_bf16.h>

typedef __bf16 bf16x8 __attribute__((ext_vector_type(8)));
typedef float f32x4 __attribute__((ext_vector_type(4)));
typedef unsigned long long u64;

#define EPSV 1e-5f

__device__ __forceinline__ float bf2f(unsigned short u){
  unsigned int x = ((unsigned int)u) << 16;
  return __builtin_bit_cast(float, x);
}
__device__ __forceinline__ unsigned short f2bf(float f){
  __bf16 b = (__bf16)f;
  return __builtin_bit_cast(unsigned short, b);
}
__device__ __forceinline__ float gelu_exact(float x){
  return 0.5f * x * (1.0f + erff(x * 0.7071067811865476f));
}
__device__ __forceinline__ void gload_lds16(const void* g, void* l){
  __builtin_amdgcn_global_load_lds((const __attribute__((address_space(1))) unsigned int*)g,
                                   (__attribute__((address_space(3))) unsigned int*)l, 16, 0, 0);
}

// ---------------------------------------------------------------------------
// 128x128 (BK=32) bf16 MFMA GEMM:  C = A[M,K] * Bt[N,K]^T (+bias)
// MODE 0: bias+exact GELU -> bf16   MODE 1: bias -> bf16
// MODE 2: *scale -> fp32            MODE 3: bias -> bf16 transposed (V->Vt)
// Batched via blockIdx.z: offsets (z>>2)*s?2 + (z&3)*s?1 (elements).
// LDS 16B-slot XOR swizzle applied on the global source addr and re-applied
// on ds_read (both-sides, G21/m201); global_load_lds dest stays linear.
// ---------------------------------------------------------------------------
template<int MODE>
__global__ __launch_bounds__(256)
void gemm_bt(const unsigned short* __restrict__ A, const unsigned short* __restrict__ B,
             const float* __restrict__ bias, void* __restrict__ Cv,
             int Kd, int lda, int ldb, int ldc,
             long sA2, long sA1, long sB2, long sB1, long sC2, long sC1,
             float scale)
{
  __shared__ unsigned short lds[2][2][4096]; // [buf][A|B][128 rows x 32 k]
  const int t = threadIdx.x;
  const int w = t >> 6, l = t & 63;
  const int z = blockIdx.z;
  A += (size_t)(z>>2)*sA2 + (size_t)(z&3)*sA1;
  B += (size_t)(z>>2)*sB2 + (size_t)(z&3)*sB1;
  const int bm0 = blockIdx.y * 128, bn0 = blockIdx.x * 128;
  const int nk = Kd >> 5;

  const int sr = l >> 2;   // staging row-within-16
  const int ss = l & 3;    // staging 16B slot

  f32x4 acc[4][4];
  #pragma unroll
  for (int i=0;i<4;++i){
    #pragma unroll
    for (int j=0;j<4;++j){ f32x4 zz = {0.f,0.f,0.f,0.f}; acc[i][j] = zz; }
  }

  const int wm = w >> 1, wn = w & 1;
  const int lr = l & 15, lg = l >> 4;

  auto stage = [&](int kt, int bb){
    const int k0 = kt << 5;
    #pragma unroll
    for (int i=0;i<2;++i){
      const int r  = w*32 + i*16 + sr;          // tile row 0..127
      const int sa = ss ^ ((r>>1)&3);           // pre-swizzled source slot
      const unsigned short* ga = A + (size_t)(bm0 + r)*lda + (k0 + sa*8);
      gload_lds16((const void*)ga, (void*)((char*)&lds[bb][0][0] + w*2048 + i*1024));
      const unsigned short* gb = B + (size_t)(bn0 + r)*ldb + (k0 + sa*8);
      gload_lds16((const void*)gb, (void*)((char*)&lds[bb][1][0] + w*2048 + i*1024));
    }
  };

  int buf = 0;
  stage(0, 0);
  for (int kt=0; kt<nk; ++kt){
    __syncthreads();                 // drains vmcnt (staging of buf) + lgkmcnt
    if (kt+1 < nk) stage(kt+1, buf^1);
    bf16x8 av[4], bv[4];
    #pragma unroll
    for (int fm=0; fm<4; ++fm){
      const int row = wm*64 + fm*16 + lr;
      const int sl  = lg ^ ((row>>1)&3);
      av[fm] = *(const bf16x8*)((const char*)&lds[buf][0][0] + row*64 + sl*16);
    }
    #pragma unroll
    for (int fn=0; fn<4; ++fn){
      const int col = wn*64 + fn*16 + lr;
      const int sl  = lg ^ ((col>>1)&3);
      bv[fn] = *(const bf16x8*)((const char*)&lds[buf][1][0] + col*64 + sl*16);
    }
    #pragma unroll
    for (int fm=0; fm<4; ++fm){
      #pragma unroll
      for (int fn=0; fn<4; ++fn)
        acc[fm][fn] = __builtin_amdgcn_mfma_f32_16x16x32_bf16(av[fm], bv[fn], acc[fm][fn], 0,0,0);
    }
    buf ^= 1;
  }

  const size_t coff = (size_t)(z>>2)*sC2 + (size_t)(z&3)*sC1;
  #pragma unroll
  for (int fm=0; fm<4; ++fm){
    #pragma unroll
    for (int fn=0; fn<4; ++fn){
      const int row0 = bm0 + wm*64 + fm*16 + lg*4;
      const int col  = bn0 + wn*64 + fn*16 + lr;
      f32x4 v = acc[fm][fn];
      if constexpr (MODE == 2){
        float* C = (float*)Cv + coff;
        #pragma unroll
        for (int j=0;j<4;++j) C[(size_t)(row0+j)*ldc + col] = v[j]*scale;
      } else if constexpr (MODE == 3){
        // Vt[b_local*1048576 + col*256 + n], col = h*1024+d (slab-adjusted via Cv)
        unsigned short* C = (unsigned short*)Cv + coff;
        const float bb = bias[col];
        u64 pack = 0;
        #pragma unroll
        for (int j=0;j<4;++j) pack |= (u64)f2bf(v[j] + bb) << (16*j);
        *(u64*)(C + (size_t)col*256 + (size_t)(row0>>8)*1048576 + (row0&255)) = pack;
      } else {
        unsigned short* C = (unsigned short*)Cv + coff;
        const float bb = bias[col];
        #pragma unroll
        for (int j=0;j<4;++j){
          float x = v[j] + bb;
          if constexpr (MODE==0) x = gelu_exact(x);
          C[(size_t)(row0+j)*ldc + col] = f2bf(x);
        }
      }
    }
  }
}

// ---------------------------------------------------------------------------
__global__ __launch_bounds__(256)
void k_convh(const float* __restrict__ in, unsigned short* __restrict__ out){
  const size_t id = (size_t)blockIdx.x*256 + threadIdx.x;
  float4 v = ((const float4*)in)[id];
  u64 pack = (u64)f2bf(v.x) | ((u64)f2bf(v.y)<<16) | ((u64)f2bf(v.z)<<32) | ((u64)f2bf(v.w)<<48);
  *(u64*)(out + id*4) = pack;
}

// W[K,N] fp32 (pointer pre-advanced by column slab) -> Wt[n_local, K] bf16
__global__ __launch_bounds__(256)
void k_tconv(const float* __restrict__ W, unsigned short* __restrict__ Wt, int Kd, int N){
  __shared__ float lt[64][65];
  const int t = threadIdx.x;
  const int n0 = blockIdx.x*64, k0 = blockIdx.y*64;
  #pragma unroll
  for (int i=0;i<16;++i){
    int lin = i*256 + t; int r = lin>>6, c = lin&63;
    lt[r][c] = W[(size_t)(k0+r)*N + n0 + c];
  }
  __syncthreads();
  #pragma unroll
  for (int i=0;i<16;++i){
    int lin = i*256 + t; int n = lin>>6, k = lin&63;
    Wt[(size_t)(n0+n)*Kd + k0 + k] = f2bf(lt[k][n]);
  }
}

__global__ __launch_bounds__(256)
void k_softmax(const float* __restrict__ S, unsigned short* __restrict__ P){
  const int t = threadIdx.x, w = t>>6, l = t&63;
  const size_t row = (size_t)blockIdx.x*4 + w;
  float4 v = *(const float4*)(S + row*256 + l*4);
  float m = fmaxf(fmaxf(v.x,v.y), fmaxf(v.z,v.w));
  #pragma unroll
  for (int off=32; off; off>>=1) m = fmaxf(m, __shfl_xor(m, off));
  float e0 = expf(v.x-m), e1 = expf(v.y-m), e2 = expf(v.z-m), e3 = expf(v.w-m);
  float s = e0+e1+e2+e3;
  #pragma unroll
  for (int off=32; off; off>>=1) s += __shfl_xor(s, off);
  const float inv = 1.0f/s;
  u64 pack = (u64)f2bf(e0*inv) | ((u64)f2bf(e1*inv)<<16) | ((u64)f2bf(e2*inv)<<32) | ((u64)f2bf(e3*inv)<<48);
  *(u64*)(P + row*256 + l*4) = pack;
}

__device__ __forceinline__ void blkred2(float& a, float& b, float* sred, int t){
  #pragma unroll
  for (int off=32; off; off>>=1){ a += __shfl_xor(a, off); b += __shfl_xor(b, off); }
  __syncthreads();
  if ((t&63)==0){ sred[(t>>6)*2] = a; sred[(t>>6)*2+1] = b; }
  __syncthreads();
  a = sred[0]+sred[2]+sred[4]+sred[6];
  b = sred[1]+sred[3]+sred[5]+sred[7];
}

// Per (b_local, group of 32 rows): accumulate mean_n of both LN chains.
// intf is fp32 here. Partials indexed by global batch (g0 + b_local).
__global__ __launch_bounds__(256)
void k_stats(const float* __restrict__ h, const float* __restrict__ intf,
             const unsigned short* __restrict__ sp,
             const float* __restrict__ g_pfs, const float* __restrict__ b_pfs,
             const float* __restrict__ g_sfs, const float* __restrict__ b_sfs,
             float* __restrict__ part_p, float* __restrict__ part_s, int g0)
{
  __shared__ float sred[8];
  const int bl = blockIdx.x, grp = blockIdx.y, t = threadIdx.x;
  float zacc[20], wacc[16];
  #pragma unroll
  for (int j=0;j<20;++j) zacc[j]=0.f;
  #pragma unroll
  for (int j=0;j<16;++j) wacc[j]=0.f;
  for (int rr=0; rr<32; ++rr){
    const size_t r = (size_t)bl*256 + grp*32 + rr;   // row within group chunk
    float hv[4], iv[16], sv[16];
    #pragma unroll
    for (int j=0;j<4;++j) hv[j] = h[r*1024 + j*256 + t];
    float s1=0.f, s2=0.f;
    #pragma unroll
    for (int j=0;j<16;++j){ float x = intf[r*4096 + j*256 + t]; iv[j]=x; s1+=x; s2+=x*x; }
    blkred2(s1,s2,sred,t);
    const float m1 = s1*(1.f/4096.f);
    const float rs1 = rsqrtf(fmaxf(s2*(1.f/4096.f) - m1*m1, 0.f) + EPSV);
    float t1=0.f, t2=0.f;
    #pragma unroll
    for (int j=0;j<4;++j){ t1 += hv[j]; t2 += hv[j]*hv[j]; }
    #pragma unroll
    for (int j=0;j<16;++j){ float y = (iv[j]-m1)*rs1; iv[j]=y; t1+=y; t2+=y*y; }
    blkred2(t1,t2,sred,t);
    const float m2 = t1*(1.f/5120.f);
    const float rs2 = rsqrtf(fmaxf(t2*(1.f/5120.f) - m2*m2, 0.f) + EPSV);
    #pragma unroll
    for (int j=0;j<4;++j){ int idx = j*256+t; zacc[j] += ((hv[j]-m2)*rs2)*g_pfs[idx] + b_pfs[idx]; }
    #pragma unroll
    for (int j=0;j<16;++j){ int idx = 1024 + j*256+t; zacc[4+j] += ((iv[j]-m2)*rs2)*g_pfs[idx] + b_pfs[idx]; }
    float u1=0.f, u2=0.f;
    #pragma unroll
    for (int j=0;j<16;++j){ float x = bf2f(sp[r*4096 + j*256 + t]); sv[j]=x; u1+=x; u2+=x*x; }
    blkred2(u1,u2,sred,t);
    const float m3 = u1*(1.f/4096.f);
    const float rs3 = rsqrtf(fmaxf(u2*(1.f/4096.f) - m3*m3, 0.f) + EPSV);
    #pragma unroll
    for (int j=0;j<16;++j){ int idx = j*256+t; wacc[j] += ((sv[j]-m3)*rs3)*g_sfs[idx] + b_sfs[idx]; }
  }
  const size_t pb = (size_t)(g0 + bl)*8 + grp;
  #pragma unroll
  for (int j=0;j<20;++j) part_p[pb*5120 + j*256 + t] = zacc[j];
  #pragma unroll
  for (int j=0;j<16;++j) part_s[pb*4096 + j*256 + t] = wacc[j];
}

__global__ __launch_bounds__(256)
void k_reduce(const float* __restrict__ part_p, const float* __restrict__ part_s,
              float* __restrict__ xbar, float* __restrict__ ybar){
  int id = blockIdx.x*256 + threadIdx.x;
  if (id < 32*5120){
    const int b = id / 5120, i = id % 5120;
    float s = 0.f;
    for (int g=0; g<8; ++g) s += part_p[((size_t)b*8+g)*5120 + i];
    xbar[(size_t)b*5120 + i] = s * (1.f/256.f);
  } else {
    id -= 32*5120;
    const int b = id / 4096, i = id % 4096;
    float s = 0.f;
    for (int g=0; g<8; ++g) s += part_s[((size_t)b*8+g)*4096 + i];
    ybar[(size_t)b*4096 + i] = s * (1.f/256.f);
  }
}

// tpre = xbar@Wpfs + bpfs ; spre = ybar@Wsfs + bsfs  (weights read once)
__global__ __launch_bounds__(256)
void k_proj(const float* __restrict__ xbar, const float* __restrict__ ybar,
            const float* __restrict__ Wpfs, const float* __restrict__ bpfs,
            const float* __restrict__ Wsfs, const float* __restrict__ bsfs,
            float* __restrict__ tpre, float* __restrict__ spre){
  const int bid = blockIdx.x, t = threadIdx.x;
  const int path = bid >> 6;
  const int col = (bid & 63)*16 + (t & 15);
  const int bp = t >> 4;                 // 0..15 -> batches bp, bp+16
  const int K = path ? 4096 : 5120;
  const float* X = path ? ybar : xbar;
  const float* W = path ? Wsfs : Wpfs;
  float a0 = 0.f, a1 = 0.f;
  for (int i = 0; i < K; ++i){
    float wv = W[(size_t)i*1024 + col];
    a0 += X[(size_t)bp*K + i] * wv;
    a1 += X[(size_t)(bp+16)*K + i] * wv;
  }
  const float bb = path ? bsfs[col] : bpfs[col];
  float* dst = path ? spre : tpre;
  dst[(size_t)bp*1024 + col] = a0 + bb;
  dst[(size_t)(bp+16)*1024 + col] = a1 + bb;
}

__global__ __launch_bounds__(256)
void k_lnrow(const float* __restrict__ tpre, const float* __restrict__ spre,
             float* __restrict__ out){
  __shared__ float sred[8];
  const int id = blockIdx.x, t = threadIdx.x;
  const int path = id >> 5, b = id & 31;
  const float* src = (path ? spre : tpre) + (size_t)b*1024;
  float v[4]; float s1=0.f, s2=0.f;
  #pragma unroll
  for (int j=0;j<4;++j){ v[j] = src[j*256+t]; s1 += v[j]; s2 += v[j]*v[j]; }
  blkred2(s1,s2,sred,t);
  const float m = s1*(1.f/1024.f);
  const float rs = rsqrtf(fmaxf(s2*(1.f/1024.f)-m*m,0.f)+EPSV);
  float* dst = out + (path ? 35072 : 2304) + (size_t)b*1024;
  #pragma unroll
  for (int j=0;j<4;++j) dst[j*256+t] = (v[j]-m)*rs;
}

__global__ __launch_bounds__(256)
void k_head(const float* __restrict__ Wpc, const float* __restrict__ bpc,
            const float* __restrict__ Wc0, const float* __restrict__ bc0,
            const float* __restrict__ Wc1, const float* __restrict__ bc1,
            const float* __restrict__ Wc2, const float* __restrict__ bc2,
            float* __restrict__ out){
  __shared__ float slog[16];
  __shared__ int sy;
  const int b = blockIdx.x, t = threadIdx.x, w = t>>6, l = t&63;
  const float* pv = out + 2304 + (size_t)b*1024;
  const float* sv = out + 35072 + (size_t)b*1024;
  #pragma unroll
  for (int jj=0; jj<4; ++jj){
    const int j = w*4 + jj;
    float a = 0.f;
    for (int i=l; i<1024; i+=64) a += pv[i]*Wpc[(size_t)i*16 + j];
    #pragma unroll
    for (int off=32; off; off>>=1) a += __shfl_xor(a, off);
    if (l==0){ const float lgv = a + bpc[j]; slog[j] = lgv; out[b*16 + j] = lgv; }
  }
  __syncthreads();
  if (t==0){
    int best=0; float bvv = slog[0];
    for (int i=1;i<16;++i) if (slog[i] > bvv){ bvv = slog[i]; best = i; }
    sy = best;
  }
  __syncthreads();
  const int y = sy;
  const float* Ws[3] = {Wc0, Wc1, Wc2};
  const float* bs[3] = {bc0, bc1, bc2};
  const int nouts[3] = {8,16,32};
  const int ooff[3]  = {512, 768, 1280};
  for (int hI=0; hI<3; ++hI){
    const int no = nouts[hI];
    for (int n = w; n < no; n += 4){
      const float* wr = Ws[hI] + ((size_t)y*no + n)*1024;
      float a = 0.f;
      for (int i=l; i<1024; i+=64) a += sv[i]*wr[i];
      #pragma unroll
      for (int off=32; off; off>>=1) a += __shfl_xor(a, off);
      if (l==0) out[ooff[hI] + b*no + n] = a + bs[hI][(size_t)y*no + n];
    }
  }
}

// ---------------------------------------------------------------------------
extern "C" void kernel_launch(void* const* d_in, const int* in_sizes, int n_in,
                              void* d_out, int out_size, void* d_ws, size_t ws_size,
                              hipStream_t stream)
{
  const float* h    = (const float*)d_in[0];
  const float* Wpp  = (const float*)d_in[1];
  const float* bpp  = (const float*)d_in[2];
  const float* Wsp  = (const float*)d_in[3];
  const float* bsp  = (const float*)d_in[4];
  const float* Wq   = (const float*)d_in[5];
  const float* bq   = (const float*)d_in[6];
  const float* Wk   = (const float*)d_in[7];
  const float* bk   = (const float*)d_in[8];
  const float* Wv   = (const float*)d_in[9];
  const float* bv   = (const float*)d_in[10];
  const float* g_pfs= (const float*)d_in[11];
  const float* b_pfs= (const float*)d_in[12];
  const float* Wpfs = (const float*)d_in[13];
  const float* bpfs = (const float*)d_in[14];
  const float* g_sfs= (const float*)d_in[15];
  const float* b_sfs= (const float*)d_in[16];
  const float* Wsfs = (const float*)d_in[17];
  const float* bsfs = (const float*)d_in[18];
  const float* Wpc  = (const float*)d_in[19];
  const float* bpc  = (const float*)d_in[20];
  const float* Wc0  = (const float*)d_in[21];
  const float* bc0  = (const float*)d_in[22];
  const float* Wc1  = (const float*)d_in[23];
  const float* bc1  = (const float*)d_in[24];
  const float* Wc2  = (const float*)d_in[25];
  const float* bc2  = (const float*)d_in[26];
  float* out = (float*)d_out;
  char* ws = (char*)d_ws;
  (void)in_sizes; (void)n_in; (void)out_size;

  // ---- adaptive plan selection (host arithmetic only) ----
  const int Gs[8]  = {32,16, 8, 4, 2, 1,   1,   1};
  const int NSs[8] = {4096,4096,4096,4096,4096,4096,2048,1024};
  int G = 0, NS = 0;
  size_t oWt=0,oPp=0,oPs=0,oXb=0,oYb=0,oTp=0,oSp=0,oHb=0,oPb=0,oSb=0,oQ=0,oK=0,oVt=0,oS=0,oP=0;
  for (int pi = 0; pi < 8; ++pi){
    const size_t g = Gs[pi], ns = NSs[pi];
    size_t off = 0;
    auto alloc = [&](size_t bytes){ size_t o = off; off += (bytes + 255) & ~255ULL; return o; };
    size_t wt = alloc(ns*4096*2);
    size_t pp_ = alloc(32*8*5120*4);
    size_t ps_ = alloc(32*8*4096*4);
    size_t xb = alloc(32*5120*4);
    size_t yb = alloc(32*4096*4);
    size_t tp = alloc(32*1024*4);
    size_t sp_ = alloc(32*1024*4);
    size_t hb = alloc(g*524288);
    size_t pb = alloc(g*2097152);
    size_t sb = alloc(g*2097152);
    size_t q  = alloc(g*2097152);
    size_t k  = alloc(g*2097152);
    size_t vt = alloc(g*2097152);
    size_t s  = alloc(g*1048576);
    size_t p  = alloc(g*524288);
    if (off <= ws_size){
      G = (int)g; NS = (int)ns;
      oWt=wt; oPp=pp_; oPs=ps_; oXb=xb; oYb=yb; oTp=tp; oSp=sp_;
      oHb=hb; oPb=pb; oSb=sb; oQ=q; oK=k; oVt=vt; oS=s; oP=p;
      break;
    }
  }
  if (!G) return;   // < ~32 MiB workspace: cannot run

  unsigned short* Wt   = (unsigned short*)(ws + oWt);
  float* part_p = (float*)(ws + oPp);
  float* part_s = (float*)(ws + oPs);
  float* xbar   = (float*)(ws + oXb);
  float* ybar   = (float*)(ws + oYb);
  float* tpre   = (float*)(ws + oTp);
  float* spre   = (float*)(ws + oSp);
  unsigned short* h_bf = (unsigned short*)(ws + oHb);
  unsigned short* pp   = (unsigned short*)(ws + oPb);
  unsigned short* sp   = (unsigned short*)(ws + oSb);
  unsigned short* Q    = (unsigned short*)(ws + oQ);
  unsigned short* Kb   = (unsigned short*)(ws + oK);
  unsigned short* Vt   = (unsigned short*)(ws + oVt);
  float*          S    = (float*)(ws + oS);
  unsigned short* P    = (unsigned short*)(ws + oP);
  float*          intf = (float*)(ws + oQ);   // aliases Q+K (contiguous, both dead)

  const float scale = 1.0f/32.0f;   // hd=1024
  (void)oK;

  for (int g0 = 0; g0 < 32; g0 += G){
    const float* h_g = h + (size_t)g0*262144;
    const int M2 = G*2;                    // M/128

    hipLaunchKernelGGL(k_convh, dim3(G*256), dim3(256), 0, stream, h_g, h_bf);

    // pp = gelu(h @ Wpp + bpp)
    hipLaunchKernelGGL(k_tconv, dim3(64,16), dim3(256), 0, stream, Wpp, Wt, 1024, 4096);
    hipLaunchKernelGGL(gemm_bt<0>, dim3(32,M2,1), dim3(256), 0, stream,
                       h_bf, Wt, bpp, (void*)pp, 1024, 1024,1024,4096,
                       0L,0L,0L,0L,0L,0L, 1.f);
    // Q = pp @ Wq + bq   (pp dead after)
    for (int nso = 0; nso < 4096; nso += NS){
      hipLaunchKernelGGL(k_tconv, dim3(NS/64,64), dim3(256), 0, stream, Wq + nso, Wt, 4096, 4096);
      hipLaunchKernelGGL(gemm_bt<1>, dim3(NS/128,M2,1), dim3(256), 0, stream,
                         pp, Wt, bq + nso, (void*)(Q + nso), 4096, 4096,4096,4096,
                         0L,0L,0L,0L,0L,0L, 1.f);
    }
    // sp = gelu(h @ Wsp + bsp)   (h_bf dead after)
    hipLaunchKernelGGL(k_tconv, dim3(64,16), dim3(256), 0, stream, Wsp, Wt, 1024, 4096);
    hipLaunchKernelGGL(gemm_bt<0>, dim3(32,M2,1), dim3(256), 0, stream,
                       h_bf, Wt, bsp, (void*)sp, 1024, 1024,1024,4096,
                       0L,0L,0L,0L,0L,0L, 1.f);
    // K = sp @ Wk + bk
    for (int nso = 0; nso < 4096; nso += NS){
      hipLaunchKernelGGL(k_tconv, dim3(NS/64,64), dim3(256), 0, stream, Wk + nso, Wt, 4096, 4096);
      hipLaunchKernelGGL(gemm_bt<1>, dim3(NS/128,M2,1), dim3(256), 0, stream,
                         sp, Wt, bk + nso, (void*)(Kb + nso), 4096, 4096,4096,4096,
                         0L,0L,0L,0L,0L,0L, 1.f);
    }
    // Vt = (sp @ Wv + bv)^T per (b_local,h)
    for (int nso = 0; nso < 4096; nso += NS){
      hipLaunchKernelGGL(k_tconv, dim3(NS/64,64), dim3(256), 0, stream, Wv + nso, Wt, 4096, 4096);
      hipLaunchKernelGGL(gemm_bt<3>, dim3(NS/128,M2,1), dim3(256), 0, stream,
                         sp, Wt, bv + nso, (void*)(Vt + (size_t)nso*256), 4096, 4096,4096,256,
                         0L,0L,0L,0L,0L,0L, 1.f);
    }
    // S = scale * Q K^T  (batched z = b_local*4 + h)
    hipLaunchKernelGGL(gemm_bt<2>, dim3(2,2,G*4), dim3(256), 0, stream,
                       Q, Kb, (const float*)nullptr, (void*)S, 1024, 4096,4096,256,
                       1048576L,1024L, 1048576L,1024L, 262144L,65536L, scale);
    hipLaunchKernelGGL(k_softmax, dim3(G*256), dim3(256), 0, stream, S, P);
    // intf = P V  (fp32 out; overwrites Q+K region)
    hipLaunchKernelGGL(gemm_bt<2>, dim3(8,2,G*4), dim3(256), 0, stream,
                       P, Vt, (const float*)nullptr, (void*)intf, 256, 256,256,4096,
                       262144L,65536L, 1048576L,262144L, 1048576L,1024L, 1.f);
    // fused LN-stat partial means
    hipLaunchKernelGGL(k_stats, dim3(G,8), dim3(256), 0, stream,
                       h_g, intf, sp, g_pfs, b_pfs, g_sfs, b_sfs, part_p, part_s, g0);
  }

  hipLaunchKernelGGL(k_reduce, dim3(1152), dim3(256), 0, stream, part_p, part_s, xbar, ybar);
  hipLaunchKernelGGL(k_proj, dim3(128), dim3(256), 0, stream,
                     xbar, ybar, Wpfs, bpfs, Wsfs, bsfs, tpre, spre);
  hipLaunchKernelGGL(k_lnrow, dim3(64), dim3(256), 0, stream, tpre, spre, out);
  hipLaunchKernelGGL(k_head, dim3(32), dim3(256), 0, stream,
                     Wpc, bpc, Wc0, bc0, Wc1, bc1, Wc2, bc2, out);
}

// Round 3
// 1886.685 us; speedup vs baseline: 2.0057x; 2.0057x over previous
//
#include <hip/hip_runtime.h>
#include <hip/hip_bf16.h>

typedef __bf16 bf16x8 __attribute__((ext_vector_type(8)));
typedef float f32x4 __attribute__((ext_vector_type(4)));
typedef unsigned long long u64;

#define EPSV 1e-5f

__device__ __forceinline__ float bf2f(unsigned short u){
  unsigned int x = ((unsigned int)u) << 16;
  return __builtin_bit_cast(float, x);
}
__device__ __forceinline__ unsigned short f2bf(float f){
  __bf16 b = (__bf16)f;
  return __builtin_bit_cast(unsigned short, b);
}
__device__ __forceinline__ float gelu_exact(float x){
  return 0.5f * x * (1.0f + erff(x * 0.7071067811865476f));
}
__device__ __forceinline__ void gload_lds16(const void* g, void* l){
  __builtin_amdgcn_global_load_lds((const __attribute__((address_space(1))) unsigned int*)g,
                                   (__attribute__((address_space(3))) unsigned int*)l, 16, 0, 0);
}

// ---------------------------------------------------------------------------
// 128x128 (BK=32) bf16 MFMA GEMM:  C = A[M,K] * Bt[N,K]^T (+bias)
// MODE 0: bias+exact GELU -> bf16   MODE 1: bias -> bf16
// MODE 2: *scale -> fp32            MODE 3: bias -> bf16 transposed (V->Vt)
// Batched via blockIdx.z: offsets (z>>2)*s?2 + (z&3)*s?1 (elements).
// ---------------------------------------------------------------------------
template<int MODE>
__global__ __launch_bounds__(256)
void gemm_bt(const unsigned short* __restrict__ A, const unsigned short* __restrict__ B,
             const float* __restrict__ bias, void* __restrict__ Cv,
             int Kd, int lda, int ldb, int ldc,
             long sA2, long sA1, long sB2, long sB1, long sC2, long sC1,
             float scale)
{
  __shared__ unsigned short lds[2][2][4096]; // [buf][A|B][128 rows x 32 k]
  const int t = threadIdx.x;
  const int w = t >> 6, l = t & 63;
  const int z = blockIdx.z;
  A += (size_t)(z>>2)*sA2 + (size_t)(z&3)*sA1;
  B += (size_t)(z>>2)*sB2 + (size_t)(z&3)*sB1;
  const int bm0 = blockIdx.y * 128, bn0 = blockIdx.x * 128;
  const int nk = Kd >> 5;

  const int sr = l >> 2;   // staging row-within-16
  const int ss = l & 3;    // staging 16B slot

  f32x4 acc[4][4];
  #pragma unroll
  for (int i=0;i<4;++i){
    #pragma unroll
    for (int j=0;j<4;++j){ f32x4 zz = {0.f,0.f,0.f,0.f}; acc[i][j] = zz; }
  }

  const int wm = w >> 1, wn = w & 1;
  const int lr = l & 15, lg = l >> 4;

  auto stage = [&](int kt, int bb){
    const int k0 = kt << 5;
    #pragma unroll
    for (int i=0;i<2;++i){
      const int r  = w*32 + i*16 + sr;          // tile row 0..127
      const int sa = ss ^ ((r>>1)&3);           // pre-swizzled source slot
      const unsigned short* ga = A + (size_t)(bm0 + r)*lda + (k0 + sa*8);
      gload_lds16((const void*)ga, (void*)((char*)&lds[bb][0][0] + w*2048 + i*1024));
      const unsigned short* gb = B + (size_t)(bn0 + r)*ldb + (k0 + sa*8);
      gload_lds16((const void*)gb, (void*)((char*)&lds[bb][1][0] + w*2048 + i*1024));
    }
  };

  int buf = 0;
  stage(0, 0);
  for (int kt=0; kt<nk; ++kt){
    __syncthreads();                 // drains vmcnt (staging of buf) + lgkmcnt
    if (kt+1 < nk) stage(kt+1, buf^1);
    bf16x8 av[4], bv[4];
    #pragma unroll
    for (int fm=0; fm<4; ++fm){
      const int row = wm*64 + fm*16 + lr;
      const int sl  = lg ^ ((row>>1)&3);
      av[fm] = *(const bf16x8*)((const char*)&lds[buf][0][0] + row*64 + sl*16);
    }
    #pragma unroll
    for (int fn=0; fn<4; ++fn){
      const int col = wn*64 + fn*16 + lr;
      const int sl  = lg ^ ((col>>1)&3);
      bv[fn] = *(const bf16x8*)((const char*)&lds[buf][1][0] + col*64 + sl*16);
    }
    #pragma unroll
    for (int fm=0; fm<4; ++fm){
      #pragma unroll
      for (int fn=0; fn<4; ++fn)
        acc[fm][fn] = __builtin_amdgcn_mfma_f32_16x16x32_bf16(av[fm], bv[fn], acc[fm][fn], 0,0,0);
    }
    buf ^= 1;
  }

  const size_t coff = (size_t)(z>>2)*sC2 + (size_t)(z&3)*sC1;
  #pragma unroll
  for (int fm=0; fm<4; ++fm){
    #pragma unroll
    for (int fn=0; fn<4; ++fn){
      const int row0 = bm0 + wm*64 + fm*16 + lg*4;
      const int col  = bn0 + wn*64 + fn*16 + lr;
      f32x4 v = acc[fm][fn];
      if constexpr (MODE == 2){
        float* C = (float*)Cv + coff;
        #pragma unroll
        for (int j=0;j<4;++j) C[(size_t)(row0+j)*ldc + col] = v[j]*scale;
      } else if constexpr (MODE == 3){
        unsigned short* C = (unsigned short*)Cv + coff;
        const float bb = bias[col];
        u64 pack = 0;
        #pragma unroll
        for (int j=0;j<4;++j) pack |= (u64)f2bf(v[j] + bb) << (16*j);
        *(u64*)(C + (size_t)col*256 + (size_t)(row0>>8)*1048576 + (row0&255)) = pack;
      } else {
        unsigned short* C = (unsigned short*)Cv + coff;
        const float bb = bias[col];
        #pragma unroll
        for (int j=0;j<4;++j){
          float x = v[j] + bb;
          if constexpr (MODE==0) x = gelu_exact(x);
          C[(size_t)(row0+j)*ldc + col] = f2bf(x);
        }
      }
    }
  }
}

// ---------------------------------------------------------------------------
__global__ __launch_bounds__(256)
void k_convh(const float* __restrict__ in, unsigned short* __restrict__ out){
  const size_t id = (size_t)blockIdx.x*256 + threadIdx.x;
  float4 v = ((const float4*)in)[id];
  u64 pack = (u64)f2bf(v.x) | ((u64)f2bf(v.y)<<16) | ((u64)f2bf(v.z)<<32) | ((u64)f2bf(v.w)<<48);
  *(u64*)(out + id*4) = pack;
}

// W[K,N] fp32 (pointer pre-advanced by column slab) -> Wt[n_local, K] bf16
__global__ __launch_bounds__(256)
void k_tconv(const float* __restrict__ W, unsigned short* __restrict__ Wt, int Kd, int N){
  __shared__ float lt[64][65];
  const int t = threadIdx.x;
  const int n0 = blockIdx.x*64, k0 = blockIdx.y*64;
  #pragma unroll
  for (int i=0;i<16;++i){
    int lin = i*256 + t; int r = lin>>6, c = lin&63;
    lt[r][c] = W[(size_t)(k0+r)*N + n0 + c];
  }
  __syncthreads();
  #pragma unroll
  for (int i=0;i<16;++i){
    int lin = i*256 + t; int n = lin>>6, k = lin&63;
    Wt[(size_t)(n0+n)*Kd + k0 + k] = f2bf(lt[k][n]);
  }
}

__global__ __launch_bounds__(256)
void k_softmax(const float* __restrict__ S, unsigned short* __restrict__ P){
  const int t = threadIdx.x, w = t>>6, l = t&63;
  const size_t row = (size_t)blockIdx.x*4 + w;
  float4 v = *(const float4*)(S + row*256 + l*4);
  float m = fmaxf(fmaxf(v.x,v.y), fmaxf(v.z,v.w));
  #pragma unroll
  for (int off=32; off; off>>=1) m = fmaxf(m, __shfl_xor(m, off));
  float e0 = expf(v.x-m), e1 = expf(v.y-m), e2 = expf(v.z-m), e3 = expf(v.w-m);
  float s = e0+e1+e2+e3;
  #pragma unroll
  for (int off=32; off; off>>=1) s += __shfl_xor(s, off);
  const float inv = 1.0f/s;
  u64 pack = (u64)f2bf(e0*inv) | ((u64)f2bf(e1*inv)<<16) | ((u64)f2bf(e2*inv)<<32) | ((u64)f2bf(e3*inv)<<48);
  *(u64*)(P + row*256 + l*4) = pack;
}

__device__ __forceinline__ void blkred2(float& a, float& b, float* sred, int t){
  #pragma unroll
  for (int off=32; off; off>>=1){ a += __shfl_xor(a, off); b += __shfl_xor(b, off); }
  __syncthreads();
  if ((t&63)==0){ sred[(t>>6)*2] = a; sred[(t>>6)*2+1] = b; }
  __syncthreads();
  a = sred[0]+sred[2]+sred[4]+sred[6];
  b = sred[1]+sred[3]+sred[5]+sred[7];
}

// Per (b_local, group of 32 rows): accumulate mean_n of both LN chains.
__global__ __launch_bounds__(256)
void k_stats(const float* __restrict__ h, const float* __restrict__ intf,
             const unsigned short* __restrict__ sp,
             const float* __restrict__ g_pfs, const float* __restrict__ b_pfs,
             const float* __restrict__ g_sfs, const float* __restrict__ b_sfs,
             float* __restrict__ part_p, float* __restrict__ part_s, int g0)
{
  __shared__ float sred[8];
  const int bl = blockIdx.x, grp = blockIdx.y, t = threadIdx.x;
  float zacc[20], wacc[16];
  #pragma unroll
  for (int j=0;j<20;++j) zacc[j]=0.f;
  #pragma unroll
  for (int j=0;j<16;++j) wacc[j]=0.f;
  for (int rr=0; rr<32; ++rr){
    const size_t r = (size_t)bl*256 + grp*32 + rr;   // row within group chunk
    float hv[4], iv[16], sv[16];
    #pragma unroll
    for (int j=0;j<4;++j) hv[j] = h[r*1024 + j*256 + t];
    float s1=0.f, s2=0.f;
    #pragma unroll
    for (int j=0;j<16;++j){ float x = intf[r*4096 + j*256 + t]; iv[j]=x; s1+=x; s2+=x*x; }
    blkred2(s1,s2,sred,t);
    const float m1 = s1*(1.f/4096.f);
    const float rs1 = rsqrtf(fmaxf(s2*(1.f/4096.f) - m1*m1, 0.f) + EPSV);
    float t1=0.f, t2=0.f;
    #pragma unroll
    for (int j=0;j<4;++j){ t1 += hv[j]; t2 += hv[j]*hv[j]; }
    #pragma unroll
    for (int j=0;j<16;++j){ float y = (iv[j]-m1)*rs1; iv[j]=y; t1+=y; t2+=y*y; }
    blkred2(t1,t2,sred,t);
    const float m2 = t1*(1.f/5120.f);
    const float rs2 = rsqrtf(fmaxf(t2*(1.f/5120.f) - m2*m2, 0.f) + EPSV);
    #pragma unroll
    for (int j=0;j<4;++j){ int idx = j*256+t; zacc[j] += ((hv[j]-m2)*rs2)*g_pfs[idx] + b_pfs[idx]; }
    #pragma unroll
    for (int j=0;j<16;++j){ int idx = 1024 + j*256+t; zacc[4+j] += ((iv[j]-m2)*rs2)*g_pfs[idx] + b_pfs[idx]; }
    float u1=0.f, u2=0.f;
    #pragma unroll
    for (int j=0;j<16;++j){ float x = bf2f(sp[r*4096 + j*256 + t]); sv[j]=x; u1+=x; u2+=x*x; }
    blkred2(u1,u2,sred,t);
    const float m3 = u1*(1.f/4096.f);
    const float rs3 = rsqrtf(fmaxf(u2*(1.f/4096.f) - m3*m3, 0.f) + EPSV);
    #pragma unroll
    for (int j=0;j<16;++j){ int idx = j*256+t; wacc[j] += ((sv[j]-m3)*rs3)*g_sfs[idx] + b_sfs[idx]; }
  }
  const size_t pb = (size_t)(g0 + bl)*8 + grp;
  #pragma unroll
  for (int j=0;j<20;++j) part_p[pb*5120 + j*256 + t] = zacc[j];
  #pragma unroll
  for (int j=0;j<16;++j) part_s[pb*4096 + j*256 + t] = wacc[j];
}

__global__ __launch_bounds__(256)
void k_reduce(const float* __restrict__ part_p, const float* __restrict__ part_s,
              float* __restrict__ xbar, float* __restrict__ ybar){
  int id = blockIdx.x*256 + threadIdx.x;
  if (id < 32*5120){
    const int b = id / 5120, i = id % 5120;
    float s = 0.f;
    for (int g=0; g<8; ++g) s += part_p[((size_t)b*8+g)*5120 + i];
    xbar[(size_t)b*5120 + i] = s * (1.f/256.f);
  } else {
    id -= 32*5120;
    const int b = id / 4096, i = id % 4096;
    float s = 0.f;
    for (int g=0; g<8; ++g) s += part_s[((size_t)b*8+g)*4096 + i];
    ybar[(size_t)b*4096 + i] = s * (1.f/256.f);
  }
}

// K-split projection: pbuf[(path*40 + y*4+sub)*32 + b][col] partial dots.
// Each thread: 1 column, 32 batch accumulators, float4 X loads, coalesced W.
__global__ __launch_bounds__(256)
void k_proj_part(const float* __restrict__ xbar, const float* __restrict__ ybar,
                 const float* __restrict__ Wpfs, const float* __restrict__ Wsfs,
                 float* __restrict__ pbuf){
  const int path = blockIdx.z;
  const int y = blockIdx.y;
  if (path == 1 && y >= 8) return;
  const int Kp = path ? 4096 : 5120;
  const float* X = path ? ybar : xbar;
  const float* W = path ? Wsfs : Wpfs;
  const int t = threadIdx.x;
  const int col = blockIdx.x*64 + (t & 63);
  const int sub = t >> 6;
  const int k0 = y*512 + sub*128;
  float acc[32];
  #pragma unroll
  for (int b=0;b<32;++b) acc[b] = 0.f;
  for (int i4=0; i4<32; ++i4){
    const int k = k0 + i4*4;
    float wv0 = W[(size_t)(k  )*1024 + col];
    float wv1 = W[(size_t)(k+1)*1024 + col];
    float wv2 = W[(size_t)(k+2)*1024 + col];
    float wv3 = W[(size_t)(k+3)*1024 + col];
    #pragma unroll
    for (int b=0;b<32;++b){
      float4 xv = *(const float4*)(X + (size_t)b*Kp + k);
      acc[b] += xv.x*wv0 + xv.y*wv1 + xv.z*wv2 + xv.w*wv3;
    }
  }
  float* dst = pbuf + ((size_t)(path*40 + y*4 + sub)*32)*1024 + col;
  #pragma unroll
  for (int b=0;b<32;++b) dst[(size_t)b*1024] = acc[b];
}

__global__ __launch_bounds__(256)
void k_projred(const float* __restrict__ pbuf,
               const float* __restrict__ bpfs, const float* __restrict__ bsfs,
               float* __restrict__ tpre, float* __restrict__ spre){
  const int id = blockIdx.x*256 + threadIdx.x;     // 65536 total
  const int path = id >> 15;
  const int rem = id & 32767;
  const int b = rem >> 10, col = rem & 1023;
  const int ns = path ? 32 : 40;
  const float* src = pbuf + ((size_t)(path*40)*32 + b)*1024 + col;
  float s = path ? bsfs[col] : bpfs[col];
  for (int g=0; g<ns; ++g) s += src[(size_t)g*32*1024];
  (path ? spre : tpre)[(size_t)b*1024 + col] = s;
}

__global__ __launch_bounds__(256)
void k_lnrow(const float* __restrict__ tpre, const float* __restrict__ spre,
             float* __restrict__ out){
  __shared__ float sred[8];
  const int id = blockIdx.x, t = threadIdx.x;
  const int path = id >> 5, b = id & 31;
  const float* src = (path ? spre : tpre) + (size_t)b*1024;
  float v[4]; float s1=0.f, s2=0.f;
  #pragma unroll
  for (int j=0;j<4;++j){ v[j] = src[j*256+t]; s1 += v[j]; s2 += v[j]*v[j]; }
  blkred2(s1,s2,sred,t);
  const float m = s1*(1.f/1024.f);
  const float rs = rsqrtf(fmaxf(s2*(1.f/1024.f)-m*m,0.f)+EPSV);
  float* dst = out + (path ? 35072 : 2304) + (size_t)b*1024;
  #pragma unroll
  for (int j=0;j<4;++j) dst[j*256+t] = (v[j]-m)*rs;
}

__global__ __launch_bounds__(256)
void k_head(const float* __restrict__ Wpc, const float* __restrict__ bpc,
            const float* __restrict__ Wc0, const float* __restrict__ bc0,
            const float* __restrict__ Wc1, const float* __restrict__ bc1,
            const float* __restrict__ Wc2, const float* __restrict__ bc2,
            float* __restrict__ out){
  __shared__ float slog[16];
  __shared__ int sy;
  const int b = blockIdx.x, t = threadIdx.x, w = t>>6, l = t&63;
  const float* pv = out + 2304 + (size_t)b*1024;
  const float* sv = out + 35072 + (size_t)b*1024;
  #pragma unroll
  for (int jj=0; jj<4; ++jj){
    const int j = w*4 + jj;
    float a = 0.f;
    for (int i=l; i<1024; i+=64) a += pv[i]*Wpc[(size_t)i*16 + j];
    #pragma unroll
    for (int off=32; off; off>>=1) a += __shfl_xor(a, off);
    if (l==0){ const float lgv = a + bpc[j]; slog[j] = lgv; out[b*16 + j] = lgv; }
  }
  __syncthreads();
  if (t==0){
    int best=0; float bvv = slog[0];
    for (int i=1;i<16;++i) if (slog[i] > bvv){ bvv = slog[i]; best = i; }
    sy = best;
  }
  __syncthreads();
  const int y = sy;
  const float* Ws[3] = {Wc0, Wc1, Wc2};
  const float* bs[3] = {bc0, bc1, bc2};
  const int nouts[3] = {8,16,32};
  const int ooff[3]  = {512, 768, 1280};
  for (int hI=0; hI<3; ++hI){
    const int no = nouts[hI];
    for (int n = w; n < no; n += 4){
      const float* wr = Ws[hI] + ((size_t)y*no + n)*1024;
      float a = 0.f;
      for (int i=l; i<1024; i+=64) a += sv[i]*wr[i];
      #pragma unroll
      for (int off=32; off; off>>=1) a += __shfl_xor(a, off);
      if (l==0) out[ooff[hI] + b*no + n] = a + bs[hI][(size_t)y*no + n];
    }
  }
}

// ---------------------------------------------------------------------------
extern "C" void kernel_launch(void* const* d_in, const int* in_sizes, int n_in,
                              void* d_out, int out_size, void* d_ws, size_t ws_size,
                              hipStream_t stream)
{
  const float* h    = (const float*)d_in[0];
  const float* Wpp  = (const float*)d_in[1];
  const float* bpp  = (const float*)d_in[2];
  const float* Wsp  = (const float*)d_in[3];
  const float* bsp  = (const float*)d_in[4];
  const float* Wq   = (const float*)d_in[5];
  const float* bq   = (const float*)d_in[6];
  const float* Wk   = (const float*)d_in[7];
  const float* bk   = (const float*)d_in[8];
  const float* Wv   = (const float*)d_in[9];
  const float* bv   = (const float*)d_in[10];
  const float* g_pfs= (const float*)d_in[11];
  const float* b_pfs= (const float*)d_in[12];
  const float* Wpfs = (const float*)d_in[13];
  const float* bpfs = (const float*)d_in[14];
  const float* g_sfs= (const float*)d_in[15];
  const float* b_sfs= (const float*)d_in[16];
  const float* Wsfs = (const float*)d_in[17];
  const float* bsfs = (const float*)d_in[18];
  const float* Wpc  = (const float*)d_in[19];
  const float* bpc  = (const float*)d_in[20];
  const float* Wc0  = (const float*)d_in[21];
  const float* bc0  = (const float*)d_in[22];
  const float* Wc1  = (const float*)d_in[23];
  const float* bc1  = (const float*)d_in[24];
  const float* Wc2  = (const float*)d_in[25];
  const float* bc2  = (const float*)d_in[26];
  float* out = (float*)d_out;
  char* ws = (char*)d_ws;
  (void)in_sizes; (void)n_in; (void)out_size;

  // ---- adaptive plan selection (host arithmetic only) ----
  const int Gs[8]  = {32,16, 8, 4, 2, 1,   1,   1};
  const int NSs[8] = {4096,4096,4096,4096,4096,4096,2048,1024};
  int G = 0, NS = 0;
  size_t oWt=0,oPp=0,oPs=0,oXb=0,oYb=0,oTp=0,oSp=0,oPbf=0,oHb=0,oPb=0,oSb=0,oQ=0,oK=0,oVt=0,oS=0,oP=0;
  for (int pi = 0; pi < 8; ++pi){
    const size_t g = Gs[pi], ns = NSs[pi];
    size_t off = 0;
    auto alloc = [&](size_t bytes){ size_t o = off; off += (bytes + 255) & ~255ULL; return o; };
    size_t wt = alloc(ns*4096*2);
    size_t pp_ = alloc(32*8*5120*4);
    size_t ps_ = alloc(32*8*4096*4);
    size_t xb = alloc(32*5120*4);
    size_t yb = alloc(32*4096*4);
    size_t tp = alloc(32*1024*4);
    size_t sp_ = alloc(32*1024*4);
    size_t pbf = alloc(2*40*32*1024*4);
    size_t hb = alloc(g*524288);
    size_t pb = alloc(g*2097152);
    size_t sb = alloc(g*2097152);
    size_t q  = alloc(g*2097152);
    size_t k  = alloc(g*2097152);
    size_t vt = alloc(g*2097152);
    size_t s  = alloc(g*1048576);
    size_t p  = alloc(g*524288);
    if (off <= ws_size){
      G = (int)g; NS = (int)ns;
      oWt=wt; oPp=pp_; oPs=ps_; oXb=xb; oYb=yb; oTp=tp; oSp=sp_; oPbf=pbf;
      oHb=hb; oPb=pb; oSb=sb; oQ=q; oK=k; oVt=vt; oS=s; oP=p;
      break;
    }
  }
  if (!G) return;   // < ~42 MiB workspace: cannot run

  unsigned short* Wt   = (unsigned short*)(ws + oWt);
  float* part_p = (float*)(ws + oPp);
  float* part_s = (float*)(ws + oPs);
  float* xbar   = (float*)(ws + oXb);
  float* ybar   = (float*)(ws + oYb);
  float* tpre   = (float*)(ws + oTp);
  float* spre   = (float*)(ws + oSp);
  float* pbuf   = (float*)(ws + oPbf);
  unsigned short* h_bf = (unsigned short*)(ws + oHb);
  unsigned short* pp   = (unsigned short*)(ws + oPb);
  unsigned short* sp   = (unsigned short*)(ws + oSb);
  unsigned short* Q    = (unsigned short*)(ws + oQ);
  unsigned short* Kb   = (unsigned short*)(ws + oK);
  unsigned short* Vt   = (unsigned short*)(ws + oVt);
  float*          S    = (float*)(ws + oS);
  unsigned short* P    = (unsigned short*)(ws + oP);
  float*          intf = (float*)(ws + oQ);   // aliases Q+K (contiguous, both dead)

  const float scale = 1.0f/32.0f;   // hd=1024
  (void)oK;

  for (int g0 = 0; g0 < 32; g0 += G){
    const float* h_g = h + (size_t)g0*262144;
    const int M2 = G*2;                    // M/128

    hipLaunchKernelGGL(k_convh, dim3(G*256), dim3(256), 0, stream, h_g, h_bf);

    // pp = gelu(h @ Wpp + bpp)
    hipLaunchKernelGGL(k_tconv, dim3(64,16), dim3(256), 0, stream, Wpp, Wt, 1024, 4096);
    hipLaunchKernelGGL(gemm_bt<0>, dim3(32,M2,1), dim3(256), 0, stream,
                       h_bf, Wt, bpp, (void*)pp, 1024, 1024,1024,4096,
                       0L,0L,0L,0L,0L,0L, 1.f);
    // Q = pp @ Wq + bq   (pp dead after)
    for (int nso = 0; nso < 4096; nso += NS){
      hipLaunchKernelGGL(k_tconv, dim3(NS/64,64), dim3(256), 0, stream, Wq + nso, Wt, 4096, 4096);
      hipLaunchKernelGGL(gemm_bt<1>, dim3(NS/128,M2,1), dim3(256), 0, stream,
                         pp, Wt, bq + nso, (void*)(Q + nso), 4096, 4096,4096,4096,
                         0L,0L,0L,0L,0L,0L, 1.f);
    }
    // sp = gelu(h @ Wsp + bsp)   (h_bf dead after)
    hipLaunchKernelGGL(k_tconv, dim3(64,16), dim3(256), 0, stream, Wsp, Wt, 1024, 4096);
    hipLaunchKernelGGL(gemm_bt<0>, dim3(32,M2,1), dim3(256), 0, stream,
                       h_bf, Wt, bsp, (void*)sp, 1024, 1024,1024,4096,
                       0L,0L,0L,0L,0L,0L, 1.f);
    // K = sp @ Wk + bk
    for (int nso = 0; nso < 4096; nso += NS){
      hipLaunchKernelGGL(k_tconv, dim3(NS/64,64), dim3(256), 0, stream, Wk + nso, Wt, 4096, 4096);
      hipLaunchKernelGGL(gemm_bt<1>, dim3(NS/128,M2,1), dim3(256), 0, stream,
                         sp, Wt, bk + nso, (void*)(Kb + nso), 4096, 4096,4096,4096,
                         0L,0L,0L,0L,0L,0L, 1.f);
    }
    // Vt = (sp @ Wv + bv)^T per (b_local,h)
    for (int nso = 0; nso < 4096; nso += NS){
      hipLaunchKernelGGL(k_tconv, dim3(NS/64,64), dim3(256), 0, stream, Wv + nso, Wt, 4096, 4096);
      hipLaunchKernelGGL(gemm_bt<3>, dim3(NS/128,M2,1), dim3(256), 0, stream,
                         sp, Wt, bv + nso, (void*)(Vt + (size_t)nso*256), 4096, 4096,4096,256,
                         0L,0L,0L,0L,0L,0L, 1.f);
    }
    // S = scale * Q K^T  (batched z = b_local*4 + h)
    hipLaunchKernelGGL(gemm_bt<2>, dim3(2,2,G*4), dim3(256), 0, stream,
                       Q, Kb, (const float*)nullptr, (void*)S, 1024, 4096,4096,256,
                       1048576L,1024L, 1048576L,1024L, 262144L,65536L, scale);
    hipLaunchKernelGGL(k_softmax, dim3(G*256), dim3(256), 0, stream, S, P);
    // intf = P V  (fp32 out; overwrites Q+K region)
    hipLaunchKernelGGL(gemm_bt<2>, dim3(8,2,G*4), dim3(256), 0, stream,
                       P, Vt, (const float*)nullptr, (void*)intf, 256, 256,256,4096,
                       262144L,65536L, 1048576L,262144L, 1048576L,1024L, 1.f);
    // fused LN-stat partial means
    hipLaunchKernelGGL(k_stats, dim3(G,8), dim3(256), 0, stream,
                       h_g, intf, sp, g_pfs, b_pfs, g_sfs, b_sfs, part_p, part_s, g0);
  }

  hipLaunchKernelGGL(k_reduce, dim3(1152), dim3(256), 0, stream, part_p, part_s, xbar, ybar);
  hipLaunchKernelGGL(k_proj_part, dim3(16,10,2), dim3(256), 0, stream,
                     xbar, ybar, Wpfs, Wsfs, pbuf);
  hipLaunchKernelGGL(k_projred, dim3(256), dim3(256), 0, stream,
                     pbuf, bpfs, bsfs, tpre, spre);
  hipLaunchKernelGGL(k_lnrow, dim3(64), dim3(256), 0, stream, tpre, spre, out);
  hipLaunchKernelGGL(k_head, dim3(32), dim3(256), 0, stream,
                     Wpc, bpc, Wc0, bc0, Wc1, bc1, Wc2, bc2, out);
}

// Round 4
// 1541.577 us; speedup vs baseline: 2.4547x; 1.2239x over previous
//
#include <hip/hip_runtime.h>
#include <hip/hip_bf16.h>

typedef __bf16 bf16x8 __attribute__((ext_vector_type(8)));
typedef float f32x4 __attribute__((ext_vector_type(4)));
typedef unsigned long long u64;

#define EPSV 1e-5f

__device__ __forceinline__ float bf2f(unsigned short u){
  unsigned int x = ((unsigned int)u) << 16;
  return __builtin_bit_cast(float, x);
}
__device__ __forceinline__ unsigned short f2bf(float f){
  __bf16 b = (__bf16)f;
  return __builtin_bit_cast(unsigned short, b);
}
__device__ __forceinline__ float gelu_exact(float x){
  return 0.5f * x * (1.0f + erff(x * 0.7071067811865476f));
}
__device__ __forceinline__ void gload_lds16(const void* g, void* l){
  __builtin_amdgcn_global_load_lds((const __attribute__((address_space(1))) unsigned int*)g,
                                   (__attribute__((address_space(3))) unsigned int*)l, 16, 0, 0);
}

#define BARX() do{ __builtin_amdgcn_sched_barrier(0); __builtin_amdgcn_s_barrier(); __builtin_amdgcn_sched_barrier(0); }while(0)
#define LGKM0() do{ asm volatile("s_waitcnt lgkmcnt(0)" ::: "memory"); __builtin_amdgcn_sched_barrier(0); }while(0)

// ---------------------------------------------------------------------------
// 256x256 (BK=64) 8-wave 4-phase bf16 MFMA GEMM: C = A[M,K] * Bt[N,K]^T (+bias)
// MODE 0: bias+GELU->bf16   MODE 1: bias->bf16   MODE 3: bias->bf16 transposed (Vt)
// Schedule (per K-tile kt, dbuf d=kt&1; staging granularity = 8KB quarter,
// 2 global_load_lds per thread per phase):
//  ph1: ds_read A-quad0(8)+B-pair0(4); stage tile kt+1 A-q1 (dbuf d^1; its old
//       data A rows64-127 was last read in iter kt-1 ph3 -> safe)
//  ph2: ds_read B-pair1(4); stage kt+2 A-q0 (rows0-63 of d, read only in ph1 -> safe)
//  ph3: ds_read A-quad1(8); stage kt+2 B-q0 (B rows0-63 of d, read ph1/ph2 -> safe)
//  ph4: no reads (B-pair0 kept in regs); stage kt+2 B-q1 (read ph1/ph2 -> safe);
//       vmcnt(6) gate: everything older than the 6 loads of ph2-4 has landed,
//       i.e. tile kt+1 complete before its first ds_read. Last 2 iters: vmcnt(0).
// LDS XOR swizzle (involution on byte offset within a [128][64] half-tile):
//   phys = lin ^ (((row>>1)&7)<<4); applied on staging *global source* slot and
//   on ds_read address (both-sides). Row stride 128B; 16 lanes of a fragment
//   read spread over 8 16B-slots x 2 rows -> 2-way bank access (free).
// ---------------------------------------------------------------------------
template<int MODE>
__global__ __launch_bounds__(512, 2)
void gemm256(const unsigned short* __restrict__ A, const unsigned short* __restrict__ B,
             const float* __restrict__ bias, void* __restrict__ Cv,
             int Kd, int lda, int ldb, int ldc)
{
  __shared__ char smem[131072];  // A: [2 dbuf][2 half][128][64]b16 @0; B same @65536
  const int t = threadIdx.x;
  const int w = t >> 6, l = t & 63;
  const int wm = w >> 2, wn = w & 3;        // wave grid 2(M) x 4(N)
  const int lr = l & 15, lg = l >> 4;
  const int bm0 = blockIdx.y * 256, bn0 = blockIdx.x * 256;
  const int nk = Kd >> 6;

  const int srow = t >> 3;                   // staging row-within-quarter 0..63
  const int sslot = t & 7;                   // staging 16B slot

  f32x4 acc[8][4];
  #pragma unroll
  for (int i=0;i<8;++i){
    #pragma unroll
    for (int j=0;j<4;++j){ f32x4 zz = {0.f,0.f,0.f,0.f}; acc[i][j] = zz; }
  }
  bf16x8 a0[4][2], a1[4][2], b0[2][2], b1[2][2];

  auto stage = [&](int kt, int mat, int hf, int q){
    if (kt >= nk) return;
    const int r_h = q*64 + srow;
    const int s_ = sslot ^ ((r_h >> 1) & 7);
    const unsigned short* gp = (mat ? B + (size_t)(bn0 + hf*128 + r_h)*ldb
                                    : A + (size_t)(bm0 + hf*128 + r_h)*lda)
                               + (kt << 6) + s_*8;
    char* lp = smem + mat*65536 + (kt&1)*32768 + hf*16384 + q*8192 + t*16;
    gload_lds16((const void*)gp, (void*)lp);
  };
  auto rdA = [&](int d, int fm, int kk)->bf16x8{
    const int r = fm*16 + lr;
    const int s_ = (kk*4 + lg) ^ ((r >> 1) & 7);
    return *(const bf16x8*)(smem + d*32768 + wm*16384 + r*128 + s_*16);
  };
  auto rdB = [&](int d, int fn, int kk)->bf16x8{
    const int r = (wn&1)*64 + fn*16 + lr;
    const int s_ = (kk*4 + lg) ^ ((r >> 1) & 7);
    return *(const bf16x8*)(smem + 65536 + d*32768 + (wn>>1)*16384 + r*128 + s_*16);
  };

  // prologue: tile0 fully (8 quarters), tile1 minus A-q1 (6 quarters)
  stage(0,0,0,0); stage(0,0,1,0); stage(0,0,0,1); stage(0,0,1,1);
  stage(0,1,0,0); stage(0,1,1,0); stage(0,1,0,1); stage(0,1,1,1);
  stage(1,0,0,0); stage(1,0,1,0);
  stage(1,1,0,0); stage(1,1,1,0); stage(1,1,0,1); stage(1,1,1,1);
  asm volatile("s_waitcnt vmcnt(6)" ::: "memory");
  BARX();

  for (int kt = 0; kt < nk; ++kt){
    const int d = kt & 1;
    // ---- phase 1 ----
    #pragma unroll
    for (int fm=0; fm<4; ++fm){ a0[fm][0] = rdA(d, fm, 0); a0[fm][1] = rdA(d, fm, 1); }
    #pragma unroll
    for (int fn=0; fn<2; ++fn){ b0[fn][0] = rdB(d, fn, 0); b0[fn][1] = rdB(d, fn, 1); }
    stage(kt+1, 0, 0, 1); stage(kt+1, 0, 1, 1);
    BARX(); LGKM0();
    __builtin_amdgcn_s_setprio(1);
    #pragma unroll
    for (int fm=0; fm<4; ++fm)
      #pragma unroll
      for (int fn=0; fn<2; ++fn)
        #pragma unroll
        for (int kk=0; kk<2; ++kk)
          acc[fm][fn] = __builtin_amdgcn_mfma_f32_16x16x32_bf16(a0[fm][kk], b0[fn][kk], acc[fm][fn], 0,0,0);
    __builtin_amdgcn_s_setprio(0);
    BARX();
    // ---- phase 2 ----
    #pragma unroll
    for (int fn=0; fn<2; ++fn){ b1[fn][0] = rdB(d, fn+2, 0); b1[fn][1] = rdB(d, fn+2, 1); }
    stage(kt+2, 0, 0, 0); stage(kt+2, 0, 1, 0);
    BARX(); LGKM0();
    __builtin_amdgcn_s_setprio(1);
    #pragma unroll
    for (int fm=0; fm<4; ++fm)
      #pragma unroll
      for (int fn=0; fn<2; ++fn)
        #pragma unroll
        for (int kk=0; kk<2; ++kk)
          acc[fm][fn+2] = __builtin_amdgcn_mfma_f32_16x16x32_bf16(a0[fm][kk], b1[fn][kk], acc[fm][fn+2], 0,0,0);
    __builtin_amdgcn_s_setprio(0);
    BARX();
    // ---- phase 3 ----
    #pragma unroll
    for (int fm=0; fm<4; ++fm){ a1[fm][0] = rdA(d, fm+4, 0); a1[fm][1] = rdA(d, fm+4, 1); }
    stage(kt+2, 1, 0, 0); stage(kt+2, 1, 1, 0);
    BARX(); LGKM0();
    __builtin_amdgcn_s_setprio(1);
    #pragma unroll
    for (int fm=0; fm<4; ++fm)
      #pragma unroll
      for (int fn=0; fn<2; ++fn)
        #pragma unroll
        for (int kk=0; kk<2; ++kk)
          acc[fm+4][fn+2] = __builtin_amdgcn_mfma_f32_16x16x32_bf16(a1[fm][kk], b1[fn][kk], acc[fm+4][fn+2], 0,0,0);
    __builtin_amdgcn_s_setprio(0);
    BARX();
    // ---- phase 4 ---- (no ds_reads: reuses a1 + b0 from registers)
    stage(kt+2, 1, 0, 1); stage(kt+2, 1, 1, 1);
    BARX();
    __builtin_amdgcn_s_setprio(1);
    #pragma unroll
    for (int fm=0; fm<4; ++fm)
      #pragma unroll
      for (int fn=0; fn<2; ++fn)
        #pragma unroll
        for (int kk=0; kk<2; ++kk)
          acc[fm+4][fn] = __builtin_amdgcn_mfma_f32_16x16x32_bf16(a1[fm][kk], b0[fn][kk], acc[fm+4][fn], 0,0,0);
    __builtin_amdgcn_s_setprio(0);
    if (kt + 2 < nk) { asm volatile("s_waitcnt vmcnt(6)" ::: "memory"); }
    else             { asm volatile("s_waitcnt vmcnt(0)" ::: "memory"); }
    BARX();
  }

  // epilogue
  #pragma unroll
  for (int fm=0; fm<8; ++fm){
    #pragma unroll
    for (int fn=0; fn<4; ++fn){
      const int row0 = bm0 + wm*128 + fm*16 + lg*4;
      const int col  = bn0 + wn*64 + fn*16 + lr;
      f32x4 v = acc[fm][fn];
      if constexpr (MODE == 3){
        unsigned short* C = (unsigned short*)Cv;
        const float bb = bias[col];
        u64 pack = 0;
        #pragma unroll
        for (int j=0;j<4;++j) pack |= (u64)f2bf(v[j] + bb) << (16*j);
        *(u64*)(C + (size_t)col*256 + (size_t)(row0>>8)*1048576 + (row0&255)) = pack;
      } else {
        unsigned short* C = (unsigned short*)Cv;
        const float bb = bias[col];
        #pragma unroll
        for (int j=0;j<4;++j){
          float x = v[j] + bb;
          if constexpr (MODE==0) x = gelu_exact(x);
          C[(size_t)(row0+j)*ldc + col] = f2bf(x);
        }
      }
    }
  }
}

// ---------------------------------------------------------------------------
// 128x128 (BK=32) bf16 MFMA GEMM (kept for the small attention GEMMs)
// MODE 2: *scale -> fp32. Batched via blockIdx.z.
// ---------------------------------------------------------------------------
template<int MODE>
__global__ __launch_bounds__(256)
void gemm_bt(const unsigned short* __restrict__ A, const unsigned short* __restrict__ B,
             const float* __restrict__ bias, void* __restrict__ Cv,
             int Kd, int lda, int ldb, int ldc,
             long sA2, long sA1, long sB2, long sB1, long sC2, long sC1,
             float scale)
{
  __shared__ unsigned short lds[2][2][4096];
  const int t = threadIdx.x;
  const int w = t >> 6, l = t & 63;
  const int z = blockIdx.z;
  A += (size_t)(z>>2)*sA2 + (size_t)(z&3)*sA1;
  B += (size_t)(z>>2)*sB2 + (size_t)(z&3)*sB1;
  const int bm0 = blockIdx.y * 128, bn0 = blockIdx.x * 128;
  const int nk = Kd >> 5;

  const int sr = l >> 2;
  const int ss = l & 3;

  f32x4 acc[4][4];
  #pragma unroll
  for (int i=0;i<4;++i){
    #pragma unroll
    for (int j=0;j<4;++j){ f32x4 zz = {0.f,0.f,0.f,0.f}; acc[i][j] = zz; }
  }

  const int wm = w >> 1, wn = w & 1;
  const int lr = l & 15, lg = l >> 4;

  auto stage = [&](int kt, int bb){
    const int k0 = kt << 5;
    #pragma unroll
    for (int i=0;i<2;++i){
      const int r  = w*32 + i*16 + sr;
      const int sa = ss ^ ((r>>1)&3);
      const unsigned short* ga = A + (size_t)(bm0 + r)*lda + (k0 + sa*8);
      gload_lds16((const void*)ga, (void*)((char*)&lds[bb][0][0] + w*2048 + i*1024));
      const unsigned short* gb = B + (size_t)(bn0 + r)*ldb + (k0 + sa*8);
      gload_lds16((const void*)gb, (void*)((char*)&lds[bb][1][0] + w*2048 + i*1024));
    }
  };

  int buf = 0;
  stage(0, 0);
  for (int kt=0; kt<nk; ++kt){
    __syncthreads();
    if (kt+1 < nk) stage(kt+1, buf^1);
    bf16x8 av[4], bv[4];
    #pragma unroll
    for (int fm=0; fm<4; ++fm){
      const int row = wm*64 + fm*16 + lr;
      const int sl  = lg ^ ((row>>1)&3);
      av[fm] = *(const bf16x8*)((const char*)&lds[buf][0][0] + row*64 + sl*16);
    }
    #pragma unroll
    for (int fn=0; fn<4; ++fn){
      const int col = wn*64 + fn*16 + lr;
      const int sl  = lg ^ ((col>>1)&3);
      bv[fn] = *(const bf16x8*)((const char*)&lds[buf][1][0] + col*64 + sl*16);
    }
    #pragma unroll
    for (int fm=0; fm<4; ++fm){
      #pragma unroll
      for (int fn=0; fn<4; ++fn)
        acc[fm][fn] = __builtin_amdgcn_mfma_f32_16x16x32_bf16(av[fm], bv[fn], acc[fm][fn], 0,0,0);
    }
    buf ^= 1;
  }

  const size_t coff = (size_t)(z>>2)*sC2 + (size_t)(z&3)*sC1;
  #pragma unroll
  for (int fm=0; fm<4; ++fm){
    #pragma unroll
    for (int fn=0; fn<4; ++fn){
      const int row0 = bm0 + wm*64 + fm*16 + lg*4;
      const int col  = bn0 + wn*64 + fn*16 + lr;
      f32x4 v = acc[fm][fn];
      if constexpr (MODE == 2){
        float* C = (float*)Cv + coff;
        #pragma unroll
        for (int j=0;j<4;++j) C[(size_t)(row0+j)*ldc + col] = v[j]*scale;
      }
    }
  }
}

// ---------------------------------------------------------------------------
__global__ __launch_bounds__(256)
void k_convh(const float* __restrict__ in, unsigned short* __restrict__ out){
  const size_t id = (size_t)blockIdx.x*256 + threadIdx.x;
  float4 v = ((const float4*)in)[id];
  u64 pack = (u64)f2bf(v.x) | ((u64)f2bf(v.y)<<16) | ((u64)f2bf(v.z)<<32) | ((u64)f2bf(v.w)<<48);
  *(u64*)(out + id*4) = pack;
}

__global__ __launch_bounds__(256)
void k_tconv(const float* __restrict__ W, unsigned short* __restrict__ Wt, int Kd, int N){
  __shared__ float lt[64][65];
  const int t = threadIdx.x;
  const int n0 = blockIdx.x*64, k0 = blockIdx.y*64;
  #pragma unroll
  for (int i=0;i<16;++i){
    int lin = i*256 + t; int r = lin>>6, c = lin&63;
    lt[r][c] = W[(size_t)(k0+r)*N + n0 + c];
  }
  __syncthreads();
  #pragma unroll
  for (int i=0;i<16;++i){
    int lin = i*256 + t; int n = lin>>6, k = lin&63;
    Wt[(size_t)(n0+n)*Kd + k0 + k] = f2bf(lt[k][n]);
  }
}

__global__ __launch_bounds__(256)
void k_softmax(const float* __restrict__ S, unsigned short* __restrict__ P){
  const int t = threadIdx.x, w = t>>6, l = t&63;
  const size_t row = (size_t)blockIdx.x*4 + w;
  float4 v = *(const float4*)(S + row*256 + l*4);
  float m = fmaxf(fmaxf(v.x,v.y), fmaxf(v.z,v.w));
  #pragma unroll
  for (int off=32; off; off>>=1) m = fmaxf(m, __shfl_xor(m, off));
  float e0 = expf(v.x-m), e1 = expf(v.y-m), e2 = expf(v.z-m), e3 = expf(v.w-m);
  float s = e0+e1+e2+e3;
  #pragma unroll
  for (int off=32; off; off>>=1) s += __shfl_xor(s, off);
  const float inv = 1.0f/s;
  u64 pack = (u64)f2bf(e0*inv) | ((u64)f2bf(e1*inv)<<16) | ((u64)f2bf(e2*inv)<<32) | ((u64)f2bf(e3*inv)<<48);
  *(u64*)(P + row*256 + l*4) = pack;
}

__device__ __forceinline__ void blkred2(float& a, float& b, float* sred, int t){
  #pragma unroll
  for (int off=32; off; off>>=1){ a += __shfl_xor(a, off); b += __shfl_xor(b, off); }
  __syncthreads();
  if ((t&63)==0){ sred[(t>>6)*2] = a; sred[(t>>6)*2+1] = b; }
  __syncthreads();
  a = sred[0]+sred[2]+sred[4]+sred[6];
  b = sred[1]+sred[3]+sred[5]+sred[7];
}

__global__ __launch_bounds__(256)
void k_stats(const float* __restrict__ h, const float* __restrict__ intf,
             const unsigned short* __restrict__ sp,
             const float* __restrict__ g_pfs, const float* __restrict__ b_pfs,
             const float* __restrict__ g_sfs, const float* __restrict__ b_sfs,
             float* __restrict__ part_p, float* __restrict__ part_s, int g0)
{
  __shared__ float sred[8];
  const int bl = blockIdx.x, grp = blockIdx.y, t = threadIdx.x;
  float zacc[20], wacc[16];
  #pragma unroll
  for (int j=0;j<20;++j) zacc[j]=0.f;
  #pragma unroll
  for (int j=0;j<16;++j) wacc[j]=0.f;
  for (int rr=0; rr<32; ++rr){
    const size_t r = (size_t)bl*256 + grp*32 + rr;
    float hv[4], iv[16], sv[16];
    #pragma unroll
    for (int j=0;j<4;++j) hv[j] = h[r*1024 + j*256 + t];
    float s1=0.f, s2=0.f;
    #pragma unroll
    for (int j=0;j<16;++j){ float x = intf[r*4096 + j*256 + t]; iv[j]=x; s1+=x; s2+=x*x; }
    blkred2(s1,s2,sred,t);
    const float m1 = s1*(1.f/4096.f);
    const float rs1 = rsqrtf(fmaxf(s2*(1.f/4096.f) - m1*m1, 0.f) + EPSV);
    float t1=0.f, t2=0.f;
    #pragma unroll
    for (int j=0;j<4;++j){ t1 += hv[j]; t2 += hv[j]*hv[j]; }
    #pragma unroll
    for (int j=0;j<16;++j){ float y = (iv[j]-m1)*rs1; iv[j]=y; t1+=y; t2+=y*y; }
    blkred2(t1,t2,sred,t);
    const float m2 = t1*(1.f/5120.f);
    const float rs2 = rsqrtf(fmaxf(t2*(1.f/5120.f) - m2*m2, 0.f) + EPSV);
    #pragma unroll
    for (int j=0;j<4;++j){ int idx = j*256+t; zacc[j] += ((hv[j]-m2)*rs2)*g_pfs[idx] + b_pfs[idx]; }
    #pragma unroll
    for (int j=0;j<16;++j){ int idx = 1024 + j*256+t; zacc[4+j] += ((iv[j]-m2)*rs2)*g_pfs[idx] + b_pfs[idx]; }
    float u1=0.f, u2=0.f;
    #pragma unroll
    for (int j=0;j<16;++j){ float x = bf2f(sp[r*4096 + j*256 + t]); sv[j]=x; u1+=x; u2+=x*x; }
    blkred2(u1,u2,sred,t);
    const float m3 = u1*(1.f/4096.f);
    const float rs3 = rsqrtf(fmaxf(u2*(1.f/4096.f) - m3*m3, 0.f) + EPSV);
    #pragma unroll
    for (int j=0;j<16;++j){ int idx = j*256+t; wacc[j] += ((sv[j]-m3)*rs3)*g_sfs[idx] + b_sfs[idx]; }
  }
  const size_t pb = (size_t)(g0 + bl)*8 + grp;
  #pragma unroll
  for (int j=0;j<20;++j) part_p[pb*5120 + j*256 + t] = zacc[j];
  #pragma unroll
  for (int j=0;j<16;++j) part_s[pb*4096 + j*256 + t] = wacc[j];
}

__global__ __launch_bounds__(256)
void k_reduce(const float* __restrict__ part_p, const float* __restrict__ part_s,
              float* __restrict__ xbar, float* __restrict__ ybar){
  int id = blockIdx.x*256 + threadIdx.x;
  if (id < 32*5120){
    const int b = id / 5120, i = id % 5120;
    float s = 0.f;
    for (int g=0; g<8; ++g) s += part_p[((size_t)b*8+g)*5120 + i];
    xbar[(size_t)b*5120 + i] = s * (1.f/256.f);
  } else {
    id -= 32*5120;
    const int b = id / 4096, i = id % 4096;
    float s = 0.f;
    for (int g=0; g<8; ++g) s += part_s[((size_t)b*8+g)*4096 + i];
    ybar[(size_t)b*4096 + i] = s * (1.f/256.f);
  }
}

__global__ __launch_bounds__(256)
void k_proj_part(const float* __restrict__ xbar, const float* __restrict__ ybar,
                 const float* __restrict__ Wpfs, const float* __restrict__ Wsfs,
                 float* __restrict__ pbuf){
  const int path = blockIdx.z;
  const int y = blockIdx.y;
  if (path == 1 && y >= 8) return;
  const int Kp = path ? 4096 : 5120;
  const float* X = path ? ybar : xbar;
  const float* W = path ? Wsfs : Wpfs;
  const int t = threadIdx.x;
  const int col = blockIdx.x*64 + (t & 63);
  const int sub = t >> 6;
  const int k0 = y*512 + sub*128;
  float acc[32];
  #pragma unroll
  for (int b=0;b<32;++b) acc[b] = 0.f;
  for (int i4=0; i4<32; ++i4){
    const int k = k0 + i4*4;
    float wv0 = W[(size_t)(k  )*1024 + col];
    float wv1 = W[(size_t)(k+1)*1024 + col];
    float wv2 = W[(size_t)(k+2)*1024 + col];
    float wv3 = W[(size_t)(k+3)*1024 + col];
    #pragma unroll
    for (int b=0;b<32;++b){
      float4 xv = *(const float4*)(X + (size_t)b*Kp + k);
      acc[b] += xv.x*wv0 + xv.y*wv1 + xv.z*wv2 + xv.w*wv3;
    }
  }
  float* dst = pbuf + ((size_t)(path*40 + y*4 + sub)*32)*1024 + col;
  #pragma unroll
  for (int b=0;b<32;++b) dst[(size_t)b*1024] = acc[b];
}

__global__ __launch_bounds__(256)
void k_projred(const float* __restrict__ pbuf,
               const float* __restrict__ bpfs, const float* __restrict__ bsfs,
               float* __restrict__ tpre, float* __restrict__ spre){
  const int id = blockIdx.x*256 + threadIdx.x;
  const int path = id >> 15;
  const int rem = id & 32767;
  const int b = rem >> 10, col = rem & 1023;
  const int ns = path ? 32 : 40;
  const float* src = pbuf + ((size_t)(path*40)*32 + b)*1024 + col;
  float s = path ? bsfs[col] : bpfs[col];
  for (int g=0; g<ns; ++g) s += src[(size_t)g*32*1024];
  (path ? spre : tpre)[(size_t)b*1024 + col] = s;
}

__global__ __launch_bounds__(256)
void k_lnrow(const float* __restrict__ tpre, const float* __restrict__ spre,
             float* __restrict__ out){
  __shared__ float sred[8];
  const int id = blockIdx.x, t = threadIdx.x;
  const int path = id >> 5, b = id & 31;
  const float* src = (path ? spre : tpre) + (size_t)b*1024;
  float v[4]; float s1=0.f, s2=0.f;
  #pragma unroll
  for (int j=0;j<4;++j){ v[j] = src[j*256+t]; s1 += v[j]; s2 += v[j]*v[j]; }
  blkred2(s1,s2,sred,t);
  const float m = s1*(1.f/1024.f);
  const float rs = rsqrtf(fmaxf(s2*(1.f/1024.f)-m*m,0.f)+EPSV);
  float* dst = out + (path ? 35072 : 2304) + (size_t)b*1024;
  #pragma unroll
  for (int j=0;j<4;++j) dst[j*256+t] = (v[j]-m)*rs;
}

__global__ __launch_bounds__(256)
void k_head(const float* __restrict__ Wpc, const float* __restrict__ bpc,
            const float* __restrict__ Wc0, const float* __restrict__ bc0,
            const float* __restrict__ Wc1, const float* __restrict__ bc1,
            const float* __restrict__ Wc2, const float* __restrict__ bc2,
            float* __restrict__ out){
  __shared__ float slog[16];
  __shared__ int sy;
  const int b = blockIdx.x, t = threadIdx.x, w = t>>6, l = t&63;
  const float* pv = out + 2304 + (size_t)b*1024;
  const float* sv = out + 35072 + (size_t)b*1024;
  #pragma unroll
  for (int jj=0; jj<4; ++jj){
    const int j = w*4 + jj;
    float a = 0.f;
    for (int i=l; i<1024; i+=64) a += pv[i]*Wpc[(size_t)i*16 + j];
    #pragma unroll
    for (int off=32; off; off>>=1) a += __shfl_xor(a, off);
    if (l==0){ const float lgv = a + bpc[j]; slog[j] = lgv; out[b*16 + j] = lgv; }
  }
  __syncthreads();
  if (t==0){
    int best=0; float bvv = slog[0];
    for (int i=1;i<16;++i) if (slog[i] > bvv){ bvv = slog[i]; best = i; }
    sy = best;
  }
  __syncthreads();
  const int y = sy;
  const float* Ws[3] = {Wc0, Wc1, Wc2};
  const float* bs[3] = {bc0, bc1, bc2};
  const int nouts[3] = {8,16,32};
  const int ooff[3]  = {512, 768, 1280};
  for (int hI=0; hI<3; ++hI){
    const int no = nouts[hI];
    for (int n = w; n < no; n += 4){
      const float* wr = Ws[hI] + ((size_t)y*no + n)*1024;
      float a = 0.f;
      for (int i=l; i<1024; i+=64) a += sv[i]*wr[i];
      #pragma unroll
      for (int off=32; off; off>>=1) a += __shfl_xor(a, off);
      if (l==0) out[ooff[hI] + b*no + n] = a + bs[hI][(size_t)y*no + n];
    }
  }
}

// ---------------------------------------------------------------------------
extern "C" void kernel_launch(void* const* d_in, const int* in_sizes, int n_in,
                              void* d_out, int out_size, void* d_ws, size_t ws_size,
                              hipStream_t stream)
{
  const float* h    = (const float*)d_in[0];
  const float* Wpp  = (const float*)d_in[1];
  const float* bpp  = (const float*)d_in[2];
  const float* Wsp  = (const float*)d_in[3];
  const float* bsp  = (const float*)d_in[4];
  const float* Wq   = (const float*)d_in[5];
  const float* bq   = (const float*)d_in[6];
  const float* Wk   = (const float*)d_in[7];
  const float* bk   = (const float*)d_in[8];
  const float* Wv   = (const float*)d_in[9];
  const float* bv   = (const float*)d_in[10];
  const float* g_pfs= (const float*)d_in[11];
  const float* b_pfs= (const float*)d_in[12];
  const float* Wpfs = (const float*)d_in[13];
  const float* bpfs = (const float*)d_in[14];
  const float* g_sfs= (const float*)d_in[15];
  const float* b_sfs= (const float*)d_in[16];
  const float* Wsfs = (const float*)d_in[17];
  const float* bsfs = (const float*)d_in[18];
  const float* Wpc  = (const float*)d_in[19];
  const float* bpc  = (const float*)d_in[20];
  const float* Wc0  = (const float*)d_in[21];
  const float* bc0  = (const float*)d_in[22];
  const float* Wc1  = (const float*)d_in[23];
  const float* bc1  = (const float*)d_in[24];
  const float* Wc2  = (const float*)d_in[25];
  const float* bc2  = (const float*)d_in[26];
  float* out = (float*)d_out;
  char* ws = (char*)d_ws;
  (void)in_sizes; (void)n_in; (void)out_size;

  // ---- adaptive plan selection (host arithmetic only) ----
  const int Gs[8]  = {32,16, 8, 4, 2, 1,   1,   1};
  const int NSs[8] = {4096,4096,4096,4096,4096,4096,2048,1024};
  int G = 0, NS = 0;
  size_t oWt=0,oPp=0,oPs=0,oXb=0,oYb=0,oTp=0,oSp=0,oPbf=0,oHb=0,oPb=0,oSb=0,oQ=0,oK=0,oVt=0,oS=0,oP=0;
  for (int pi = 0; pi < 8; ++pi){
    const size_t g = Gs[pi], ns = NSs[pi];
    size_t off = 0;
    auto alloc = [&](size_t bytes){ size_t o = off; off += (bytes + 255) & ~255ULL; return o; };
    size_t wt = alloc(ns*4096*2);
    size_t pp_ = alloc(32*8*5120*4);
    size_t ps_ = alloc(32*8*4096*4);
    size_t xb = alloc(32*5120*4);
    size_t yb = alloc(32*4096*4);
    size_t tp = alloc(32*1024*4);
    size_t sp_ = alloc(32*1024*4);
    size_t pbf = alloc(2*40*32*1024*4);
    size_t hb = alloc(g*524288);
    size_t pb = alloc(g*2097152);
    size_t sb = alloc(g*2097152);
    size_t q  = alloc(g*2097152);
    size_t k  = alloc(g*2097152);
    size_t vt = alloc(g*2097152);
    size_t s  = alloc(g*1048576);
    size_t p  = alloc(g*524288);
    if (off <= ws_size){
      G = (int)g; NS = (int)ns;
      oWt=wt; oPp=pp_; oPs=ps_; oXb=xb; oYb=yb; oTp=tp; oSp=sp_; oPbf=pbf;
      oHb=hb; oPb=pb; oSb=sb; oQ=q; oK=k; oVt=vt; oS=s; oP=p;
      break;
    }
  }
  if (!G) return;

  unsigned short* Wt   = (unsigned short*)(ws + oWt);
  float* part_p = (float*)(ws + oPp);
  float* part_s = (float*)(ws + oPs);
  float* xbar   = (float*)(ws + oXb);
  float* ybar   = (float*)(ws + oYb);
  float* tpre   = (float*)(ws + oTp);
  float* spre   = (float*)(ws + oSp);
  float* pbuf   = (float*)(ws + oPbf);
  unsigned short* h_bf = (unsigned short*)(ws + oHb);
  unsigned short* pp   = (unsigned short*)(ws + oPb);
  unsigned short* sp   = (unsigned short*)(ws + oSb);
  unsigned short* Q    = (unsigned short*)(ws + oQ);
  unsigned short* Kb   = (unsigned short*)(ws + oK);
  unsigned short* Vt   = (unsigned short*)(ws + oVt);
  float*          S    = (float*)(ws + oS);
  unsigned short* P    = (unsigned short*)(ws + oP);
  float*          intf = (float*)(ws + oQ);   // aliases Q+K (contiguous, both dead)

  const float scale = 1.0f/32.0f;
  (void)oK;

  for (int g0 = 0; g0 < 32; g0 += G){
    const float* h_g = h + (size_t)g0*262144;

    hipLaunchKernelGGL(k_convh, dim3(G*256), dim3(256), 0, stream, h_g, h_bf);

    // pp = gelu(h @ Wpp + bpp)
    hipLaunchKernelGGL(k_tconv, dim3(64,16), dim3(256), 0, stream, Wpp, Wt, 1024, 4096);
    hipLaunchKernelGGL(gemm256<0>, dim3(16,G), dim3(512), 0, stream,
                       h_bf, Wt, bpp, (void*)pp, 1024, 1024,1024,4096);
    // Q = pp @ Wq + bq
    for (int nso = 0; nso < 4096; nso += NS){
      hipLaunchKernelGGL(k_tconv, dim3(NS/64,64), dim3(256), 0, stream, Wq + nso, Wt, 4096, 4096);
      hipLaunchKernelGGL(gemm256<1>, dim3(NS/256,G), dim3(512), 0, stream,
                         pp, Wt, bq + nso, (void*)(Q + nso), 4096, 4096,4096,4096);
    }
    // sp = gelu(h @ Wsp + bsp)
    hipLaunchKernelGGL(k_tconv, dim3(64,16), dim3(256), 0, stream, Wsp, Wt, 1024, 4096);
    hipLaunchKernelGGL(gemm256<0>, dim3(16,G), dim3(512), 0, stream,
                       h_bf, Wt, bsp, (void*)sp, 1024, 1024,1024,4096);
    // K = sp @ Wk + bk
    for (int nso = 0; nso < 4096; nso += NS){
      hipLaunchKernelGGL(k_tconv, dim3(NS/64,64), dim3(256), 0, stream, Wk + nso, Wt, 4096, 4096);
      hipLaunchKernelGGL(gemm256<1>, dim3(NS/256,G), dim3(512), 0, stream,
                         sp, Wt, bk + nso, (void*)(Kb + nso), 4096, 4096,4096,4096);
    }
    // Vt = (sp @ Wv + bv)^T per (b_local,h)
    for (int nso = 0; nso < 4096; nso += NS){
      hipLaunchKernelGGL(k_tconv, dim3(NS/64,64), dim3(256), 0, stream, Wv + nso, Wt, 4096, 4096);
      hipLaunchKernelGGL(gemm256<3>, dim3(NS/256,G), dim3(512), 0, stream,
                         sp, Wt, bv + nso, (void*)(Vt + (size_t)nso*256), 4096, 4096,4096,256);
    }
    // S = scale * Q K^T  (batched z = b_local*4 + h)
    hipLaunchKernelGGL(gemm_bt<2>, dim3(2,2,G*4), dim3(256), 0, stream,
                       Q, Kb, (const float*)nullptr, (void*)S, 1024, 4096,4096,256,
                       1048576L,1024L, 1048576L,1024L, 262144L,65536L, scale);
    hipLaunchKernelGGL(k_softmax, dim3(G*256), dim3(256), 0, stream, S, P);
    // intf = P V  (fp32 out; overwrites Q+K region)
    hipLaunchKernelGGL(gemm_bt<2>, dim3(8,2,G*4), dim3(256), 0, stream,
                       P, Vt, (const float*)nullptr, (void*)intf, 256, 256,256,4096,
                       262144L,65536L, 1048576L,262144L, 1048576L,1024L, 1.f);
    // fused LN-stat partial means
    hipLaunchKernelGGL(k_stats, dim3(G,8), dim3(256), 0, stream,
                       h_g, intf, sp, g_pfs, b_pfs, g_sfs, b_sfs, part_p, part_s, g0);
  }

  hipLaunchKernelGGL(k_reduce, dim3(1152), dim3(256), 0, stream, part_p, part_s, xbar, ybar);
  hipLaunchKernelGGL(k_proj_part, dim3(16,10,2), dim3(256), 0, stream,
                     xbar, ybar, Wpfs, Wsfs, pbuf);
  hipLaunchKernelGGL(k_projred, dim3(256), dim3(256), 0, stream,
                     pbuf, bpfs, bsfs, tpre, spre);
  hipLaunchKernelGGL(k_lnrow, dim3(64), dim3(256), 0, stream, tpre, spre, out);
  hipLaunchKernelGGL(k_head, dim3(32), dim3(256), 0, stream,
                     Wpc, bpc, Wc0, bc0, Wc1, bc1, Wc2, bc2, out);
}

// Round 5
// 1510.666 us; speedup vs baseline: 2.5049x; 1.0205x over previous
//
#include <hip/hip_runtime.h>
#include <hip/hip_bf16.h>

typedef __bf16 bf16x8 __attribute__((ext_vector_type(8)));
typedef float f32x4 __attribute__((ext_vector_type(4)));
typedef unsigned long long u64;

#define EPSV 1e-5f

__device__ __forceinline__ float bf2f(unsigned short u){
  unsigned int x = ((unsigned int)u) << 16;
  return __builtin_bit_cast(float, x);
}
__device__ __forceinline__ unsigned short f2bf(float f){
  __bf16 b = (__bf16)f;
  return __builtin_bit_cast(unsigned short, b);
}
__device__ __forceinline__ float gelu_exact(float x){
  return 0.5f * x * (1.0f + erff(x * 0.7071067811865476f));
}
__device__ __forceinline__ void gload_lds16(const void* g, void* l){
  __builtin_amdgcn_global_load_lds((const __attribute__((address_space(1))) unsigned int*)g,
                                   (__attribute__((address_space(3))) unsigned int*)l, 16, 0, 0);
}

// rule #18: sched_barrier(0) ONLY after the lgkmcnt wait (keeps MFMA from
// hoisting past it); plain s_barrier elsewhere (has unmodeled side effects,
// memory ops can't cross it -- extra sched fences were m141-style pessimization).
#define LGKM0() do{ asm volatile("s_waitcnt lgkmcnt(0)" ::: "memory"); __builtin_amdgcn_sched_barrier(0); }while(0)

// ---------------------------------------------------------------------------
// 256x256 (BK=64) 8-wave 4-phase bf16 MFMA GEMM: C = A[M,K] * Bt[N,K]^T (+bias)
// MODE 0: bias+GELU->bf16   MODE 1: bias->bf16   MODE 3: bias->bf16 transposed (Vt)
// Per K-tile kt (dbuf d=kt&1), phases:
//  ph1: rd A-rows0-63 (8) + B-pair0 (4); stage kt+1 A-q1 -> d^1
//  ph2: rd B-pair1 (4);                  stage kt+2 A-q0 -> d (rows read ph1)
//  ph3: rd A-rows64-127 (8);             stage kt+2 B-q0 -> d (rows read ph1/ph2)
//  ph4: no reads (regs);                 stage kt+2 B-q1 -> d (rows read ph1/ph2)
//       vmcnt gate: 6 in flight = tile kt+1 fully landed before next iter.
// Safety: every stage targets a region whose readers all passed their own
// lgkmcnt(0) before the previous phase-end barrier. vmcnt/lgkmcnt asm has
// "memory" clobber so ds ops can't cross; s_barrier blocks all memory motion.
// LDS XOR swizzle (involution): slot ^= (row>>1)&7, applied on the staging
// *global source* slot and on ds_read (both-sides, G21).
// ---------------------------------------------------------------------------
template<int MODE>
__global__ __launch_bounds__(512, 2)
void gemm256(const unsigned short* __restrict__ A, const unsigned short* __restrict__ B,
             const float* __restrict__ bias, void* __restrict__ Cv,
             int Kd, int lda, int ldb, int ldc)
{
  __shared__ char smem[131072];  // A: [2 dbuf][2 half][128][64]b16 @0; B same @65536
  const int t = threadIdx.x;
  const int w = t >> 6, l = t & 63;
  const int wm = w >> 2, wn = w & 3;        // wave grid 2(M) x 4(N)
  const int lr = l & 15, lg = l >> 4;
  // XCD-aware bijective block swizzle (nwg%8==0 guaranteed by launch shapes)
  const int nbx = gridDim.x;
  const int nwg = nbx * gridDim.y;
  int bid = blockIdx.y*nbx + blockIdx.x;
  if ((nwg & 7) == 0) bid = (bid & 7)*(nwg >> 3) + (bid >> 3);
  const int bm0 = (bid / nbx) * 256, bn0 = (bid % nbx) * 256;
  const int nk = Kd >> 6;

  const int srow = t >> 3;                   // staging row-within-quarter 0..63
  const int sslot = t & 7;                   // staging 16B slot

  f32x4 acc[8][4];
  #pragma unroll
  for (int i=0;i<8;++i){
    #pragma unroll
    for (int j=0;j<4;++j){ f32x4 zz = {0.f,0.f,0.f,0.f}; acc[i][j] = zz; }
  }
  bf16x8 a0[4][2], a1[4][2], b0[2][2], b1[2][2];

  auto stage = [&](int kt, int mat, int hf, int q){
    if (kt >= nk) return;
    const int r_h = q*64 + srow;
    const int s_ = sslot ^ ((r_h >> 1) & 7);
    const unsigned short* gp = (mat ? B + (size_t)(bn0 + hf*128 + r_h)*ldb
                                    : A + (size_t)(bm0 + hf*128 + r_h)*lda)
                               + (kt << 6) + s_*8;
    char* lp = smem + mat*65536 + (kt&1)*32768 + hf*16384 + q*8192 + t*16;
    gload_lds16((const void*)gp, (void*)lp);
  };
  auto rdA = [&](int d, int fm, int kk)->bf16x8{
    const int r = fm*16 + lr;
    const int s_ = (kk*4 + lg) ^ ((r >> 1) & 7);
    return *(const bf16x8*)(smem + d*32768 + wm*16384 + r*128 + s_*16);
  };
  auto rdB = [&](int d, int fn, int kk)->bf16x8{
    const int r = (wn&1)*64 + fn*16 + lr;
    const int s_ = (kk*4 + lg) ^ ((r >> 1) & 7);
    return *(const bf16x8*)(smem + 65536 + d*32768 + (wn>>1)*16384 + r*128 + s_*16);
  };

  auto ktile = [&](int kt, int d){
    // ---- phase 1 ----
    #pragma unroll
    for (int fm=0; fm<4; ++fm){ a0[fm][0] = rdA(d, fm, 0); a0[fm][1] = rdA(d, fm, 1); }
    #pragma unroll
    for (int fn=0; fn<2; ++fn){ b0[fn][0] = rdB(d, fn, 0); b0[fn][1] = rdB(d, fn, 1); }
    stage(kt+1, 0, 0, 1); stage(kt+1, 0, 1, 1);
    __builtin_amdgcn_s_barrier();
    LGKM0();
    __builtin_amdgcn_s_setprio(1);
    #pragma unroll
    for (int fm=0; fm<4; ++fm)
      #pragma unroll
      for (int fn=0; fn<2; ++fn)
        #pragma unroll
        for (int kk=0; kk<2; ++kk)
          acc[fm][fn] = __builtin_amdgcn_mfma_f32_16x16x32_bf16(a0[fm][kk], b0[fn][kk], acc[fm][fn], 0,0,0);
    __builtin_amdgcn_s_setprio(0);
    __builtin_amdgcn_s_barrier();
    // ---- phase 2 ----
    #pragma unroll
    for (int fn=0; fn<2; ++fn){ b1[fn][0] = rdB(d, fn+2, 0); b1[fn][1] = rdB(d, fn+2, 1); }
    stage(kt+2, 0, 0, 0); stage(kt+2, 0, 1, 0);
    __builtin_amdgcn_s_barrier();
    LGKM0();
    __builtin_amdgcn_s_setprio(1);
    #pragma unroll
    for (int fm=0; fm<4; ++fm)
      #pragma unroll
      for (int fn=0; fn<2; ++fn)
        #pragma unroll
        for (int kk=0; kk<2; ++kk)
          acc[fm][fn+2] = __builtin_amdgcn_mfma_f32_16x16x32_bf16(a0[fm][kk], b1[fn][kk], acc[fm][fn+2], 0,0,0);
    __builtin_amdgcn_s_setprio(0);
    __builtin_amdgcn_s_barrier();
    // ---- phase 3 ----
    #pragma unroll
    for (int fm=0; fm<4; ++fm){ a1[fm][0] = rdA(d, fm+4, 0); a1[fm][1] = rdA(d, fm+4, 1); }
    stage(kt+2, 1, 0, 0); stage(kt+2, 1, 1, 0);
    __builtin_amdgcn_s_barrier();
    LGKM0();
    __builtin_amdgcn_s_setprio(1);
    #pragma unroll
    for (int fm=0; fm<4; ++fm)
      #pragma unroll
      for (int fn=0; fn<2; ++fn)
        #pragma unroll
        for (int kk=0; kk<2; ++kk)
          acc[fm+4][fn+2] = __builtin_amdgcn_mfma_f32_16x16x32_bf16(a1[fm][kk], b1[fn][kk], acc[fm+4][fn+2], 0,0,0);
    __builtin_amdgcn_s_setprio(0);
    __builtin_amdgcn_s_barrier();
    // ---- phase 4 ---- (no ds_reads: reuses a1 + b0 from registers)
    stage(kt+2, 1, 0, 1); stage(kt+2, 1, 1, 1);
    __builtin_amdgcn_s_setprio(1);
    #pragma unroll
    for (int fm=0; fm<4; ++fm)
      #pragma unroll
      for (int fn=0; fn<2; ++fn)
        #pragma unroll
        for (int kk=0; kk<2; ++kk)
          acc[fm+4][fn] = __builtin_amdgcn_mfma_f32_16x16x32_bf16(a1[fm][kk], b0[fn][kk], acc[fm+4][fn], 0,0,0);
    __builtin_amdgcn_s_setprio(0);
    if (kt + 2 < nk) { asm volatile("s_waitcnt vmcnt(6)" ::: "memory"); }
    else             { asm volatile("s_waitcnt vmcnt(0)" ::: "memory"); }
    __builtin_amdgcn_s_barrier();
  };

  // prologue: tile0 fully (8 quarters), tile1 minus A-q1 (6 quarters)
  stage(0,0,0,0); stage(0,0,1,0); stage(0,0,0,1); stage(0,0,1,1);
  stage(0,1,0,0); stage(0,1,1,0); stage(0,1,0,1); stage(0,1,1,1);
  stage(1,0,0,0); stage(1,0,1,0);
  stage(1,1,0,0); stage(1,1,1,0); stage(1,1,0,1); stage(1,1,1,1);
  asm volatile("s_waitcnt vmcnt(6)" ::: "memory");
  __builtin_amdgcn_s_barrier();

  for (int kt = 0; kt < nk; kt += 2){ ktile(kt, 0); ktile(kt+1, 1); }

  // epilogue
  #pragma unroll
  for (int fm=0; fm<8; ++fm){
    #pragma unroll
    for (int fn=0; fn<4; ++fn){
      const int row0 = bm0 + wm*128 + fm*16 + lg*4;
      const int col  = bn0 + wn*64 + fn*16 + lr;
      f32x4 v = acc[fm][fn];
      if constexpr (MODE == 3){
        unsigned short* C = (unsigned short*)Cv;
        const float bb = bias[col];
        u64 pack = 0;
        #pragma unroll
        for (int j=0;j<4;++j) pack |= (u64)f2bf(v[j] + bb) << (16*j);
        *(u64*)(C + (size_t)col*256 + (size_t)(row0>>8)*1048576 + (row0&255)) = pack;
      } else {
        unsigned short* C = (unsigned short*)Cv;
        const float bb = bias[col];
        #pragma unroll
        for (int j=0;j<4;++j){
          float x = v[j] + bb;
          if constexpr (MODE==0) x = gelu_exact(x);
          C[(size_t)(row0+j)*ldc + col] = f2bf(x);
        }
      }
    }
  }
}

// ---------------------------------------------------------------------------
// 128x128 (BK=32) bf16 MFMA GEMM (small attention GEMMs). MODE 2: *scale->fp32.
// ---------------------------------------------------------------------------
template<int MODE>
__global__ __launch_bounds__(256)
void gemm_bt(const unsigned short* __restrict__ A, const unsigned short* __restrict__ B,
             const float* __restrict__ bias, void* __restrict__ Cv,
             int Kd, int lda, int ldb, int ldc,
             long sA2, long sA1, long sB2, long sB1, long sC2, long sC1,
             float scale)
{
  __shared__ unsigned short lds[2][2][4096];
  const int t = threadIdx.x;
  const int w = t >> 6, l = t & 63;
  const int z = blockIdx.z;
  A += (size_t)(z>>2)*sA2 + (size_t)(z&3)*sA1;
  B += (size_t)(z>>2)*sB2 + (size_t)(z&3)*sB1;
  const int bm0 = blockIdx.y * 128, bn0 = blockIdx.x * 128;
  const int nk = Kd >> 5;

  const int sr = l >> 2;
  const int ss = l & 3;

  f32x4 acc[4][4];
  #pragma unroll
  for (int i=0;i<4;++i){
    #pragma unroll
    for (int j=0;j<4;++j){ f32x4 zz = {0.f,0.f,0.f,0.f}; acc[i][j] = zz; }
  }

  const int wm = w >> 1, wn = w & 1;
  const int lr = l & 15, lg = l >> 4;

  auto stage = [&](int kt, int bb){
    const int k0 = kt << 5;
    #pragma unroll
    for (int i=0;i<2;++i){
      const int r  = w*32 + i*16 + sr;
      const int sa = ss ^ ((r>>1)&3);
      const unsigned short* ga = A + (size_t)(bm0 + r)*lda + (k0 + sa*8);
      gload_lds16((const void*)ga, (void*)((char*)&lds[bb][0][0] + w*2048 + i*1024));
      const unsigned short* gb = B + (size_t)(bn0 + r)*ldb + (k0 + sa*8);
      gload_lds16((const void*)gb, (void*)((char*)&lds[bb][1][0] + w*2048 + i*1024));
    }
  };

  int buf = 0;
  stage(0, 0);
  for (int kt=0; kt<nk; ++kt){
    __syncthreads();
    if (kt+1 < nk) stage(kt+1, buf^1);
    bf16x8 av[4], bv[4];
    #pragma unroll
    for (int fm=0; fm<4; ++fm){
      const int row = wm*64 + fm*16 + lr;
      const int sl  = lg ^ ((row>>1)&3);
      av[fm] = *(const bf16x8*)((const char*)&lds[buf][0][0] + row*64 + sl*16);
    }
    #pragma unroll
    for (int fn=0; fn<4; ++fn){
      const int col = wn*64 + fn*16 + lr;
      const int sl  = lg ^ ((col>>1)&3);
      bv[fn] = *(const bf16x8*)((const char*)&lds[buf][1][0] + col*64 + sl*16);
    }
    #pragma unroll
    for (int fm=0; fm<4; ++fm){
      #pragma unroll
      for (int fn=0; fn<4; ++fn)
        acc[fm][fn] = __builtin_amdgcn_mfma_f32_16x16x32_bf16(av[fm], bv[fn], acc[fm][fn], 0,0,0);
    }
    buf ^= 1;
  }

  const size_t coff = (size_t)(z>>2)*sC2 + (size_t)(z&3)*sC1;
  #pragma unroll
  for (int fm=0; fm<4; ++fm){
    #pragma unroll
    for (int fn=0; fn<4; ++fn){
      const int row0 = bm0 + wm*64 + fm*16 + lg*4;
      const int col  = bn0 + wn*64 + fn*16 + lr;
      f32x4 v = acc[fm][fn];
      if constexpr (MODE == 2){
        float* C = (float*)Cv + coff;
        #pragma unroll
        for (int j=0;j<4;++j) C[(size_t)(row0+j)*ldc + col] = v[j]*scale;
      }
    }
  }
}

// ---------------------------------------------------------------------------
__global__ __launch_bounds__(256)
void k_convh(const float* __restrict__ in, unsigned short* __restrict__ out){
  const size_t id = (size_t)blockIdx.x*256 + threadIdx.x;
  float4 v = ((const float4*)in)[id];
  u64 pack = (u64)f2bf(v.x) | ((u64)f2bf(v.y)<<16) | ((u64)f2bf(v.z)<<32) | ((u64)f2bf(v.w)<<48);
  *(u64*)(out + id*4) = pack;
}

__global__ __launch_bounds__(256)
void k_tconv(const float* __restrict__ W, unsigned short* __restrict__ Wt, int Kd, int N){
  __shared__ float lt[64][65];
  const int t = threadIdx.x;
  const int n0 = blockIdx.x*64, k0 = blockIdx.y*64;
  #pragma unroll
  for (int i=0;i<16;++i){
    int lin = i*256 + t; int r = lin>>6, c = lin&63;
    lt[r][c] = W[(size_t)(k0+r)*N + n0 + c];
  }
  __syncthreads();
  #pragma unroll
  for (int i=0;i<16;++i){
    int lin = i*256 + t; int n = lin>>6, k = lin&63;
    Wt[(size_t)(n0+n)*Kd + k0 + k] = f2bf(lt[k][n]);
  }
}

__global__ __launch_bounds__(256)
void k_softmax(const float* __restrict__ S, unsigned short* __restrict__ P){
  const int t = threadIdx.x, w = t>>6, l = t&63;
  const size_t row = (size_t)blockIdx.x*4 + w;
  float4 v = *(const float4*)(S + row*256 + l*4);
  float m = fmaxf(fmaxf(v.x,v.y), fmaxf(v.z,v.w));
  #pragma unroll
  for (int off=32; off; off>>=1) m = fmaxf(m, __shfl_xor(m, off));
  float e0 = expf(v.x-m), e1 = expf(v.y-m), e2 = expf(v.z-m), e3 = expf(v.w-m);
  float s = e0+e1+e2+e3;
  #pragma unroll
  for (int off=32; off; off>>=1) s += __shfl_xor(s, off);
  const float inv = 1.0f/s;
  u64 pack = (u64)f2bf(e0*inv) | ((u64)f2bf(e1*inv)<<16) | ((u64)f2bf(e2*inv)<<32) | ((u64)f2bf(e3*inv)<<48);
  *(u64*)(P + row*256 + l*4) = pack;
}

__device__ __forceinline__ void blkred2(float& a, float& b, float* sred, int t){
  #pragma unroll
  for (int off=32; off; off>>=1){ a += __shfl_xor(a, off); b += __shfl_xor(b, off); }
  __syncthreads();
  if ((t&63)==0){ sred[(t>>6)*2] = a; sred[(t>>6)*2+1] = b; }
  __syncthreads();
  a = sred[0]+sred[2]+sred[4]+sred[6];
  b = sred[1]+sred[3]+sred[5]+sred[7];
}

__global__ __launch_bounds__(256)
void k_stats(const float* __restrict__ h, const float* __restrict__ intf,
             const unsigned short* __restrict__ sp,
             const float* __restrict__ g_pfs, const float* __restrict__ b_pfs,
             const float* __restrict__ g_sfs, const float* __restrict__ b_sfs,
             float* __restrict__ part_p, float* __restrict__ part_s, int g0)
{
  __shared__ float sred[8];
  const int bl = blockIdx.x, grp = blockIdx.y, t = threadIdx.x;
  float zacc[20], wacc[16];
  #pragma unroll
  for (int j=0;j<20;++j) zacc[j]=0.f;
  #pragma unroll
  for (int j=0;j<16;++j) wacc[j]=0.f;
  for (int rr=0; rr<32; ++rr){
    const size_t r = (size_t)bl*256 + grp*32 + rr;
    float hv[4], iv[16], sv[16];
    #pragma unroll
    for (int j=0;j<4;++j) hv[j] = h[r*1024 + j*256 + t];
    float s1=0.f, s2=0.f;
    #pragma unroll
    for (int j=0;j<16;++j){ float x = intf[r*4096 + j*256 + t]; iv[j]=x; s1+=x; s2+=x*x; }
    blkred2(s1,s2,sred,t);
    const float m1 = s1*(1.f/4096.f);
    const float rs1 = rsqrtf(fmaxf(s2*(1.f/4096.f) - m1*m1, 0.f) + EPSV);
    float t1=0.f, t2=0.f;
    #pragma unroll
    for (int j=0;j<4;++j){ t1 += hv[j]; t2 += hv[j]*hv[j]; }
    #pragma unroll
    for (int j=0;j<16;++j){ float y = (iv[j]-m1)*rs1; iv[j]=y; t1+=y; t2+=y*y; }
    blkred2(t1,t2,sred,t);
    const float m2 = t1*(1.f/5120.f);
    const float rs2 = rsqrtf(fmaxf(t2*(1.f/5120.f) - m2*m2, 0.f) + EPSV);
    #pragma unroll
    for (int j=0;j<4;++j){ int idx = j*256+t; zacc[j] += ((hv[j]-m2)*rs2)*g_pfs[idx] + b_pfs[idx]; }
    #pragma unroll
    for (int j=0;j<16;++j){ int idx = 1024 + j*256+t; zacc[4+j] += ((iv[j]-m2)*rs2)*g_pfs[idx] + b_pfs[idx]; }
    float u1=0.f, u2=0.f;
    #pragma unroll
    for (int j=0;j<16;++j){ float x = bf2f(sp[r*4096 + j*256 + t]); sv[j]=x; u1+=x; u2+=x*x; }
    blkred2(u1,u2,sred,t);
    const float m3 = u1*(1.f/4096.f);
    const float rs3 = rsqrtf(fmaxf(u2*(1.f/4096.f) - m3*m3, 0.f) + EPSV);
    #pragma unroll
    for (int j=0;j<16;++j){ int idx = j*256+t; wacc[j] += ((sv[j]-m3)*rs3)*g_sfs[idx] + b_sfs[idx]; }
  }
  const size_t pb = (size_t)(g0 + bl)*8 + grp;
  #pragma unroll
  for (int j=0;j<20;++j) part_p[pb*5120 + j*256 + t] = zacc[j];
  #pragma unroll
  for (int j=0;j<16;++j) part_s[pb*4096 + j*256 + t] = wacc[j];
}

__global__ __launch_bounds__(256)
void k_reduce(const float* __restrict__ part_p, const float* __restrict__ part_s,
              float* __restrict__ xbar, float* __restrict__ ybar){
  int id = blockIdx.x*256 + threadIdx.x;
  if (id < 32*5120){
    const int b = id / 5120, i = id % 5120;
    float s = 0.f;
    for (int g=0; g<8; ++g) s += part_p[((size_t)b*8+g)*5120 + i];
    xbar[(size_t)b*5120 + i] = s * (1.f/256.f);
  } else {
    id -= 32*5120;
    const int b = id / 4096, i = id % 4096;
    float s = 0.f;
    for (int g=0; g<8; ++g) s += part_s[((size_t)b*8+g)*4096 + i];
    ybar[(size_t)b*4096 + i] = s * (1.f/256.f);
  }
}

__global__ __launch_bounds__(256)
void k_proj_part(const float* __restrict__ xbar, const float* __restrict__ ybar,
                 const float* __restrict__ Wpfs, const float* __restrict__ Wsfs,
                 float* __restrict__ pbuf){
  const int path = blockIdx.z;
  const int y = blockIdx.y;
  if (path == 1 && y >= 8) return;
  const int Kp = path ? 4096 : 5120;
  const float* X = path ? ybar : xbar;
  const float* W = path ? Wsfs : Wpfs;
  const int t = threadIdx.x;
  const int col = blockIdx.x*64 + (t & 63);
  const int sub = t >> 6;
  const int k0 = y*512 + sub*128;
  float acc[32];
  #pragma unroll
  for (int b=0;b<32;++b) acc[b] = 0.f;
  for (int i4=0; i4<32; ++i4){
    const int k = k0 + i4*4;
    float wv0 = W[(size_t)(k  )*1024 + col];
    float wv1 = W[(size_t)(k+1)*1024 + col];
    float wv2 = W[(size_t)(k+2)*1024 + col];
    float wv3 = W[(size_t)(k+3)*1024 + col];
    #pragma unroll
    for (int b=0;b<32;++b){
      float4 xv = *(const float4*)(X + (size_t)b*Kp + k);
      acc[b] += xv.x*wv0 + xv.y*wv1 + xv.z*wv2 + xv.w*wv3;
    }
  }
  float* dst = pbuf + ((size_t)(path*40 + y*4 + sub)*32)*1024 + col;
  #pragma unroll
  for (int b=0;b<32;++b) dst[(size_t)b*1024] = acc[b];
}

__global__ __launch_bounds__(256)
void k_projred(const float* __restrict__ pbuf,
               const float* __restrict__ bpfs, const float* __restrict__ bsfs,
               float* __restrict__ tpre, float* __restrict__ spre){
  const int id = blockIdx.x*256 + threadIdx.x;
  const int path = id >> 15;
  const int rem = id & 32767;
  const int b = rem >> 10, col = rem & 1023;
  const int ns = path ? 32 : 40;
  const float* src = pbuf + ((size_t)(path*40)*32 + b)*1024 + col;
  float s = path ? bsfs[col] : bpfs[col];
  for (int g=0; g<ns; ++g) s += src[(size_t)g*32*1024];
  (path ? spre : tpre)[(size_t)b*1024 + col] = s;
}

__global__ __launch_bounds__(256)
void k_lnrow(const float* __restrict__ tpre, const float* __restrict__ spre,
             float* __restrict__ out){
  __shared__ float sred[8];
  const int id = blockIdx.x, t = threadIdx.x;
  const int path = id >> 5, b = id & 31;
  const float* src = (path ? spre : tpre) + (size_t)b*1024;
  float v[4]; float s1=0.f, s2=0.f;
  #pragma unroll
  for (int j=0;j<4;++j){ v[j] = src[j*256+t]; s1 += v[j]; s2 += v[j]*v[j]; }
  blkred2(s1,s2,sred,t);
  const float m = s1*(1.f/1024.f);
  const float rs = rsqrtf(fmaxf(s2*(1.f/1024.f)-m*m,0.f)+EPSV);
  float* dst = out + (path ? 35072 : 2304) + (size_t)b*1024;
  #pragma unroll
  for (int j=0;j<4;++j) dst[j*256+t] = (v[j]-m)*rs;
}

__global__ __launch_bounds__(256)
void k_head(const float* __restrict__ Wpc, const float* __restrict__ bpc,
            const float* __restrict__ Wc0, const float* __restrict__ bc0,
            const float* __restrict__ Wc1, const float* __restrict__ bc1,
            const float* __restrict__ Wc2, const float* __restrict__ bc2,
            float* __restrict__ out){
  __shared__ float slog[16];
  __shared__ int sy;
  const int b = blockIdx.x, t = threadIdx.x, w = t>>6, l = t&63;
  const float* pv = out + 2304 + (size_t)b*1024;
  const float* sv = out + 35072 + (size_t)b*1024;
  #pragma unroll
  for (int jj=0; jj<4; ++jj){
    const int j = w*4 + jj;
    float a = 0.f;
    for (int i=l; i<1024; i+=64) a += pv[i]*Wpc[(size_t)i*16 + j];
    #pragma unroll
    for (int off=32; off; off>>=1) a += __shfl_xor(a, off);
    if (l==0){ const float lgv = a + bpc[j]; slog[j] = lgv; out[b*16 + j] = lgv; }
  }
  __syncthreads();
  if (t==0){
    int best=0; float bvv = slog[0];
    for (int i=1;i<16;++i) if (slog[i] > bvv){ bvv = slog[i]; best = i; }
    sy = best;
  }
  __syncthreads();
  const int y = sy;
  const float* Ws[3] = {Wc0, Wc1, Wc2};
  const float* bs[3] = {bc0, bc1, bc2};
  const int nouts[3] = {8,16,32};
  const int ooff[3]  = {512, 768, 1280};
  for (int hI=0; hI<3; ++hI){
    const int no = nouts[hI];
    for (int n = w; n < no; n += 4){
      const float* wr = Ws[hI] + ((size_t)y*no + n)*1024;
      float a = 0.f;
      for (int i=l; i<1024; i+=64) a += sv[i]*wr[i];
      #pragma unroll
      for (int off=32; off; off>>=1) a += __shfl_xor(a, off);
      if (l==0) out[ooff[hI] + b*no + n] = a + bs[hI][(size_t)y*no + n];
    }
  }
}

// ---------------------------------------------------------------------------
extern "C" void kernel_launch(void* const* d_in, const int* in_sizes, int n_in,
                              void* d_out, int out_size, void* d_ws, size_t ws_size,
                              hipStream_t stream)
{
  const float* h    = (const float*)d_in[0];
  const float* Wpp  = (const float*)d_in[1];
  const float* bpp  = (const float*)d_in[2];
  const float* Wsp  = (const float*)d_in[3];
  const float* bsp  = (const float*)d_in[4];
  const float* Wq   = (const float*)d_in[5];
  const float* bq   = (const float*)d_in[6];
  const float* Wk   = (const float*)d_in[7];
  const float* bk   = (const float*)d_in[8];
  const float* Wv   = (const float*)d_in[9];
  const float* bv   = (const float*)d_in[10];
  const float* g_pfs= (const float*)d_in[11];
  const float* b_pfs= (const float*)d_in[12];
  const float* Wpfs = (const float*)d_in[13];
  const float* bpfs = (const float*)d_in[14];
  const float* g_sfs= (const float*)d_in[15];
  const float* b_sfs= (const float*)d_in[16];
  const float* Wsfs = (const float*)d_in[17];
  const float* bsfs = (const float*)d_in[18];
  const float* Wpc  = (const float*)d_in[19];
  const float* bpc  = (const float*)d_in[20];
  const float* Wc0  = (const float*)d_in[21];
  const float* bc0  = (const float*)d_in[22];
  const float* Wc1  = (const float*)d_in[23];
  const float* bc1  = (const float*)d_in[24];
  const float* Wc2  = (const float*)d_in[25];
  const float* bc2  = (const float*)d_in[26];
  float* out = (float*)d_out;
  char* ws = (char*)d_ws;
  (void)in_sizes; (void)n_in; (void)out_size;

  // ---- adaptive plan selection (host arithmetic only) ----
  // HOIST=1: pre-convert all five weight matrices once (no per-group tconv).
  struct PlanT { int G, NS, hoist; };
  const PlanT plans[10] = {
    {32,4096,0},{16,4096,1},{16,4096,0},{8,4096,1},{8,4096,0},
    {4,4096,0},{2,4096,0},{1,4096,0},{1,2048,0},{1,1024,0}};
  int G = 0, NS = 0, HOIST = 0;
  size_t oWt=0,oWpp=0,oWsp=0,oWq=0,oWk=0,oWv=0;
  size_t oPp=0,oPs=0,oXb=0,oYb=0,oTp=0,oSp=0,oPbf=0,oHb=0,oPb=0,oSb=0,oQ=0,oK=0,oVt=0,oS=0,oP=0;
  for (int pi = 0; pi < 10; ++pi){
    const size_t g = plans[pi].G, ns = plans[pi].NS;
    const int hoist = plans[pi].hoist;
    size_t off = 0;
    auto alloc = [&](size_t bytes){ size_t o = off; off += (bytes + 255) & ~255ULL; return o; };
    size_t wt=0, w1=0, w2=0, w3=0, w4=0, w5=0;
    if (hoist){
      w1 = alloc(1024ULL*4096*2); w2 = alloc(1024ULL*4096*2);
      w3 = alloc(4096ULL*4096*2); w4 = alloc(4096ULL*4096*2); w5 = alloc(4096ULL*4096*2);
    } else {
      wt = alloc(ns*4096*2);
    }
    size_t pp_ = alloc(32*8*5120*4);
    size_t ps_ = alloc(32*8*4096*4);
    size_t xb = alloc(32*5120*4);
    size_t yb = alloc(32*4096*4);
    size_t tp = alloc(32*1024*4);
    size_t sp_ = alloc(32*1024*4);
    size_t pbf = alloc(2*40*32*1024*4);
    size_t hb = alloc(g*524288);
    size_t pb = alloc(g*2097152);
    size_t sb = alloc(g*2097152);
    size_t q  = alloc(g*2097152);
    size_t k  = alloc(g*2097152);
    size_t vt = alloc(g*2097152);
    size_t s  = alloc(g*1048576);
    size_t p  = alloc(g*524288);
    if (off <= ws_size){
      G = (int)g; NS = (int)ns; HOIST = hoist;
      oWt=wt; oWpp=w1; oWsp=w2; oWq=w3; oWk=w4; oWv=w5;
      oPp=pp_; oPs=ps_; oXb=xb; oYb=yb; oTp=tp; oSp=sp_; oPbf=pbf;
      oHb=hb; oPb=pb; oSb=sb; oQ=q; oK=k; oVt=vt; oS=s; oP=p;
      break;
    }
  }
  if (!G) return;

  unsigned short* Wt   = (unsigned short*)(ws + oWt);
  unsigned short* WppT = (unsigned short*)(ws + oWpp);
  unsigned short* WspT = (unsigned short*)(ws + oWsp);
  unsigned short* WqT  = (unsigned short*)(ws + oWq);
  unsigned short* WkT  = (unsigned short*)(ws + oWk);
  unsigned short* WvT  = (unsigned short*)(ws + oWv);
  float* part_p = (float*)(ws + oPp);
  float* part_s = (float*)(ws + oPs);
  float* xbar   = (float*)(ws + oXb);
  float* ybar   = (float*)(ws + oYb);
  float* tpre   = (float*)(ws + oTp);
  float* spre   = (float*)(ws + oSp);
  float* pbuf   = (float*)(ws + oPbf);
  unsigned short* h_bf = (unsigned short*)(ws + oHb);
  unsigned short* pp   = (unsigned short*)(ws + oPb);
  unsigned short* sp   = (unsigned short*)(ws + oSb);
  unsigned short* Q    = (unsigned short*)(ws + oQ);
  unsigned short* Kb   = (unsigned short*)(ws + oK);
  unsigned short* Vt   = (unsigned short*)(ws + oVt);
  float*          S    = (float*)(ws + oS);
  unsigned short* P    = (unsigned short*)(ws + oP);
  float*          intf = (float*)(ws + oQ);   // aliases Q+K (contiguous, both dead)

  const float scale = 1.0f/32.0f;
  (void)oK;

  if (HOIST){
    hipLaunchKernelGGL(k_tconv, dim3(64,16), dim3(256), 0, stream, Wpp, WppT, 1024, 4096);
    hipLaunchKernelGGL(k_tconv, dim3(64,16), dim3(256), 0, stream, Wsp, WspT, 1024, 4096);
    hipLaunchKernelGGL(k_tconv, dim3(64,64), dim3(256), 0, stream, Wq, WqT, 4096, 4096);
    hipLaunchKernelGGL(k_tconv, dim3(64,64), dim3(256), 0, stream, Wk, WkT, 4096, 4096);
    hipLaunchKernelGGL(k_tconv, dim3(64,64), dim3(256), 0, stream, Wv, WvT, 4096, 4096);
  }

  for (int g0 = 0; g0 < 32; g0 += G){
    const float* h_g = h + (size_t)g0*262144;

    hipLaunchKernelGGL(k_convh, dim3(G*256), dim3(256), 0, stream, h_g, h_bf);

    // pp = gelu(h @ Wpp + bpp)
    if (!HOIST) hipLaunchKernelGGL(k_tconv, dim3(64,16), dim3(256), 0, stream, Wpp, Wt, 1024, 4096);
    hipLaunchKernelGGL(gemm256<0>, dim3(16,G), dim3(512), 0, stream,
                       h_bf, HOIST?WppT:Wt, bpp, (void*)pp, 1024, 1024,1024,4096);
    // Q = pp @ Wq + bq
    if (HOIST){
      hipLaunchKernelGGL(gemm256<1>, dim3(16,G), dim3(512), 0, stream,
                         pp, WqT, bq, (void*)Q, 4096, 4096,4096,4096);
    } else {
      for (int nso = 0; nso < 4096; nso += NS){
        hipLaunchKernelGGL(k_tconv, dim3(NS/64,64), dim3(256), 0, stream, Wq + nso, Wt, 4096, 4096);
        hipLaunchKernelGGL(gemm256<1>, dim3(NS/256,G), dim3(512), 0, stream,
                           pp, Wt, bq + nso, (void*)(Q + nso), 4096, 4096,4096,4096);
      }
    }
    // sp = gelu(h @ Wsp + bsp)
    if (!HOIST) hipLaunchKernelGGL(k_tconv, dim3(64,16), dim3(256), 0, stream, Wsp, Wt, 1024, 4096);
    hipLaunchKernelGGL(gemm256<0>, dim3(16,G), dim3(512), 0, stream,
                       h_bf, HOIST?WspT:Wt, bsp, (void*)sp, 1024, 1024,1024,4096);
    // K = sp @ Wk + bk
    if (HOIST){
      hipLaunchKernelGGL(gemm256<1>, dim3(16,G), dim3(512), 0, stream,
                         sp, WkT, bk, (void*)Kb, 4096, 4096,4096,4096);
    } else {
      for (int nso = 0; nso < 4096; nso += NS){
        hipLaunchKernelGGL(k_tconv, dim3(NS/64,64), dim3(256), 0, stream, Wk + nso, Wt, 4096, 4096);
        hipLaunchKernelGGL(gemm256<1>, dim3(NS/256,G), dim3(512), 0, stream,
                           sp, Wt, bk + nso, (void*)(Kb + nso), 4096, 4096,4096,4096);
      }
    }
    // Vt = (sp @ Wv + bv)^T per (b_local,h)
    if (HOIST){
      hipLaunchKernelGGL(gemm256<3>, dim3(16,G), dim3(512), 0, stream,
                         sp, WvT, bv, (void*)Vt, 4096, 4096,4096,256);
    } else {
      for (int nso = 0; nso < 4096; nso += NS){
        hipLaunchKernelGGL(k_tconv, dim3(NS/64,64), dim3(256), 0, stream, Wv + nso, Wt, 4096, 4096);
        hipLaunchKernelGGL(gemm256<3>, dim3(NS/256,G), dim3(512), 0, stream,
                           sp, Wt, bv + nso, (void*)(Vt + (size_t)nso*256), 4096, 4096,4096,256);
      }
    }
    // S = scale * Q K^T  (batched z = b_local*4 + h)
    hipLaunchKernelGGL(gemm_bt<2>, dim3(2,2,G*4), dim3(256), 0, stream,
                       Q, Kb, (const float*)nullptr, (void*)S, 1024, 4096,4096,256,
                       1048576L,1024L, 1048576L,1024L, 262144L,65536L, scale);
    hipLaunchKernelGGL(k_softmax, dim3(G*256), dim3(256), 0, stream, S, P);
    // intf = P V  (fp32 out; overwrites Q+K region)
    hipLaunchKernelGGL(gemm_bt<2>, dim3(8,2,G*4), dim3(256), 0, stream,
                       P, Vt, (const float*)nullptr, (void*)intf, 256, 256,256,4096,
                       262144L,65536L, 1048576L,262144L, 1048576L,1024L, 1.f);
    // fused LN-stat partial means
    hipLaunchKernelGGL(k_stats, dim3(G,8), dim3(256), 0, stream,
                       h_g, intf, sp, g_pfs, b_pfs, g_sfs, b_sfs, part_p, part_s, g0);
  }

  hipLaunchKernelGGL(k_reduce, dim3(1152), dim3(256), 0, stream, part_p, part_s, xbar, ybar);
  hipLaunchKernelGGL(k_proj_part, dim3(16,10,2), dim3(256), 0, stream,
                     xbar, ybar, Wpfs, Wsfs, pbuf);
  hipLaunchKernelGGL(k_projred, dim3(256), dim3(256), 0, stream,
                     pbuf, bpfs, bsfs, tpre, spre);
  hipLaunchKernelGGL(k_lnrow, dim3(64), dim3(256), 0, stream, tpre, spre, out);
  hipLaunchKernelGGL(k_head, dim3(32), dim3(256), 0, stream,
                     Wpc, bpc, Wc0, bc0, Wc1, bc1, Wc2, bc2, out);
}